// Round 7
// baseline (66547.150 us; speedup 1.0000x reference)
//
#include <hip/hip_runtime.h>
#include <math.h>

#define BB 32
#define TIN 256
#define TOUT 400
#define EE 512
#define AA 128
#define KSZ 31
#define PRE 256
#define DD 1024
#define NMEL 80
#define NF 32
#define KP 4356          // padded K-rows per LDS weight column

typedef _Float16 h2 __attribute__((ext_vector_type(2)));
typedef _Float16 h4 __attribute__((ext_vector_type(4)));

__device__ __forceinline__ float fast_sigmoid(float x) { return 1.f / (1.f + __expf(-x)); }
__device__ __forceinline__ float fast_tanh(float x) {
  float ax = fabsf(x);
  float e = __expf(fminf(2.f * ax, 40.f));
  return copysignf((e - 1.f) / (e + 1.f), x);
}
__device__ __forceinline__ float d2(h2 a, h2 b, float c) {
#if __has_builtin(__builtin_amdgcn_fdot2)
  return __builtin_amdgcn_fdot2(a, b, c, false);
#else
  return fmaf((float)a[0], (float)b[0], fmaf((float)a[1], (float)b[1], c));
#endif
}

// ---------------- setup kernels ----------------
// px stored k4-blocked per t: px[t][j>>2][b][j&3]
__global__ void k_prenet(const float* __restrict__ targets,
                         const float* __restrict__ w1, const float* __restrict__ b1,
                         const float* __restrict__ w2, const float* __restrict__ b2,
                         _Float16* __restrict__ px) {
  int t = blockIdx.x >> 5, b = blockIdx.x & 31, j = threadIdx.x;
  __shared__ float din[NMEL];
  __shared__ float hl[PRE];
  if (j < NMEL) din[j] = (t == 0) ? 0.f : targets[(b * TOUT + (t - 1)) * NMEL + j];
  __syncthreads();
  float s = b1[j];
#pragma unroll
  for (int k = 0; k < NMEL; ++k) s = fmaf(din[k], w1[k * PRE + j], s);
  hl[j] = fmaxf(s, 0.f);
  __syncthreads();
  float s2 = b2[j];
  for (int k = 0; k < PRE; ++k) s2 = fmaf(hl[k], w2[k * PRE + j], s2);
  px[(size_t)t * 8192 + (j >> 2) * 128 + b * 4 + (j & 3)] = (_Float16)fmaxf(s2, 0.f);
}

__global__ void k_keys(const float* __restrict__ memory, const float* __restrict__ mw,
                       const float* __restrict__ mb, _Float16* __restrict__ keys) {
  int row = blockIdx.x, a = threadIdx.x;
  __shared__ float mrow[EE];
  for (int i = a; i < EE; i += AA) mrow[i] = memory[row * EE + i];
  __syncthreads();
  float s = mb[a];
  for (int k = 0; k < EE; ++k) s = fmaf(mrow[k], mw[k * AA + a], s);
  keys[row * AA + a] = (_Float16)s;
}

__global__ void k_locM(const float* __restrict__ cw, const float* __restrict__ cb,
                       const float* __restrict__ ldw, const float* __restrict__ ldb,
                       float* __restrict__ M, float* __restrict__ Lb) {
  int a = threadIdx.x;
  for (int kk = 0; kk < KSZ; ++kk) {
    float s = 0.f;
    for (int f = 0; f < NF; ++f) s = fmaf(cw[kk * NF + f], ldw[f * AA + a], s);
    M[kk * AA + a] = s;
  }
  float s = ldb[a];
  for (int f = 0; f < NF; ++f) s = fmaf(cb[f], ldw[f * AA + a], s);
  Lb[a] = s;
}

__global__ void k_cast(const float* __restrict__ src, _Float16* __restrict__ dst, int n) {
  int i = blockIdx.x * 256 + threadIdx.x;
  if (i < n) dst[i] = (_Float16)src[i];
}

// qw [1024][128] -> qwT [128][1024] fp16
__global__ void k_castT(const float* __restrict__ qw, _Float16* __restrict__ qwT) {
  int i = blockIdx.x * 256 + threadIdx.x;  // 131072
  int k = i >> 7, a = i & 127;
  qwT[a * 1024 + k] = (_Float16)qw[k * 128 + a];
}

// proj+gate weights padded: pwp[k][128] halves, o<80 = mel, o=80 = gate
__global__ void k_permP(const float* __restrict__ pw, const float* __restrict__ gw,
                        _Float16* __restrict__ pwp) {
  int i = blockIdx.x * 256 + threadIdx.x;  // 1536*128
  int k = i >> 7, o = i & 127;
  float v = (o < 80) ? pw[k * 80 + o] : ((o == 80) ? gw[k] : 0.f);
  pwp[i] = (_Float16)v;
}

// gate-interleave + per-block-slice permute into fp16 staging:
// col p=4j+g; block B=j>>2 owns 16 cols; c=4*(j&3)+g; dst[(B*16+c)*KP + row_off+k]
__global__ void k_perm(const float* __restrict__ src, _Float16* __restrict__ dst,
                       int rows, int row_off) {
  int idx = blockIdx.x * 256 + threadIdx.x;
  int k = idx >> 10, j = idx & 1023;
  if (k >= rows) return;
  const float* s = src + (size_t)k * 4096 + j;
  int base = (j >> 2) * 16 + 4 * (j & 3);
#pragma unroll
  for (int g = 0; g < 4; ++g)
    dst[(size_t)(base + g) * KP + row_off + k] = (_Float16)s[g * 1024];
}

// ---------------- persistent decoder ----------------
struct AttnS {
  float wl[TIN + KSZ - 1];
  float qpart[512];
  float qp[AA];
  float red[TIN];
  float wsm[TIN];
  float epart[512];
  float ctxl[EE];
  float pred[512];
};

// two-level grid barrier: 8 group counters -> epoch -> 8 per-XCD doors.
// ord = 0-based barrier ordinal (3 per step, monotone).
__device__ __forceinline__ void gbar(int* bar, int ord, int tid) {
  __syncthreads();
  if (tid == 0) {
    __builtin_amdgcn_fence(__ATOMIC_RELEASE, "agent");
    int g = blockIdx.x & 7;
    int old = __hip_atomic_fetch_add(bar + g * 16, 1, __ATOMIC_RELAXED,
                                     __HIP_MEMORY_SCOPE_AGENT);
    if ((old & 31) == 31) {  // last block of my group
      int e = __hip_atomic_fetch_add(bar + 128, 1, __ATOMIC_RELAXED,
                                     __HIP_MEMORY_SCOPE_AGENT);
      if (e == 8 * ord + 7) {  // globally last: open all doors
#pragma unroll
        for (int d = 0; d < 8; ++d)
          __hip_atomic_store(bar + 144 + d * 16, ord + 1, __ATOMIC_RELAXED,
                             __HIP_MEMORY_SCOPE_AGENT);
      }
    }
    while (__hip_atomic_load(bar + 144 + g * 16, __ATOMIC_RELAXED,
                             __HIP_MEMORY_SCOPE_AGENT) < ord + 1)
      __builtin_amdgcn_s_sleep(4);
    __builtin_amdgcn_fence(__ATOMIC_ACQUIRE, "agent");
  }
  __syncthreads();
}

// LSTM phase: z = x @ W (fp16 LDS weights, gate-interleaved) -> gates -> h,c
// thread = (kq in 4, bq in 8, c in 16). x segments are k4-blocked: seg[(k>>2)*128 + b*4 + (k&3)]
// -> one contiguous 32B read per thread per 4-k group (gather-free; round-6 was
//    a 16-way scattered gather = ~58 us/step of TA address serialization).
template <int KT, int KQ, int WOFF>
__device__ __forceinline__ void lstm_phase(
    const _Float16* __restrict__ Wl, float* __restrict__ zred, float* __restrict__ zfull,
    float* __restrict__ cstL, const float* __restrict__ gbl,
    const _Float16* __restrict__ s0, int len0,
    const _Float16* __restrict__ s1,   // ctx (512)
    const _Float16* __restrict__ s2,   // h_old (1024)
    _Float16* __restrict__ hout, int B, int tid) {
  const int c = tid & 15, bq = (tid >> 4) & 7, kq = tid >> 7;
  const int b0 = bq * 4;
  const int seg01 = len0 + 512;
  const _Float16* Wrow = Wl + c * KP + WOFF;
  float a0 = 0.f, a1 = 0.f, a2 = 0.f, a3 = 0.f;
  int k = kq * KQ, kend = k + KQ;
#pragma unroll 8
  for (; k < kend; k += 4) {
    h4 w = *(const h4*)(Wrow + k);
    const _Float16* xp;
    int k0;
    if (k < len0)       { xp = s0; k0 = 0; }
    else if (k < seg01) { xp = s1; k0 = len0; }
    else                { xp = s2; k0 = seg01; }
    const _Float16* xr = xp + (((k - k0) >> 2) << 7) + b0 * 4;  // 32B contiguous
    h4 xa = *(const h4*)(xr);
    h4 xb = *(const h4*)(xr + 4);
    h4 xc = *(const h4*)(xr + 8);
    h4 xd = *(const h4*)(xr + 12);
    h2 w01 = {w[0], w[1]}, w23 = {w[2], w[3]};
    a0 = d2(w23, (h2){xa[2], xa[3]}, d2(w01, (h2){xa[0], xa[1]}, a0));
    a1 = d2(w23, (h2){xb[2], xb[3]}, d2(w01, (h2){xb[0], xb[1]}, a1));
    a2 = d2(w23, (h2){xc[2], xc[3]}, d2(w01, (h2){xc[0], xc[1]}, a2));
    a3 = d2(w23, (h2){xd[2], xd[3]}, d2(w01, (h2){xd[0], xd[1]}, a3));
  }
  // zred padded to 17 (round-6: stride 16 -> 4-way bank conflicts on store)
  zred[(kq * 32 + b0 + 0) * 17 + c] = a0;
  zred[(kq * 32 + b0 + 1) * 17 + c] = a1;
  zred[(kq * 32 + b0 + 2) * 17 + c] = a2;
  zred[(kq * 32 + b0 + 3) * 17 + c] = a3;
  __syncthreads();
  {  // 4-way kq reduction
    int cc = tid & 15, bb = tid >> 4;
    zfull[bb * 17 + cc] = zred[bb * 17 + cc] + zred[(32 + bb) * 17 + cc] +
                          zred[(64 + bb) * 17 + cc] + zred[(96 + bb) * 17 + cc];
  }
  __syncthreads();
  if (tid < 128) {
    int jj = tid >> 5, b = tid & 31;
    float zi = zfull[b * 17 + 4 * jj + 0] + gbl[4 * jj + 0];
    float zf = zfull[b * 17 + 4 * jj + 1] + gbl[4 * jj + 1];
    float zg = zfull[b * 17 + 4 * jj + 2] + gbl[4 * jj + 2];
    float zo = zfull[b * 17 + 4 * jj + 3] + gbl[4 * jj + 3];
    float ig = fast_sigmoid(zi), fg = fast_sigmoid(zf);
    float gg = fast_tanh(zg), og = fast_sigmoid(zo);
    float cn = fg * cstL[jj * 32 + b] + ig * gg;
    cstL[jj * 32 + b] = cn;
    // k4-blocked h: col = B*4+jj -> offset B*128 + b*4 + jj
    hout[B * 128 + b * 4 + jj] = (_Float16)(og * fast_tanh(cn));
  }
}

__device__ __forceinline__ void attn_phase(
    AttnS* A, const _Float16* __restrict__ mem16, const _Float16* __restrict__ keys16,
    const _Float16* __restrict__ h1,   // k4-blocked
    const _Float16* __restrict__ qwT, const float* __restrict__ qb,
    const float* __restrict__ vw, const float* __restrict__ vb,
    const float* __restrict__ Mf, const float* __restrict__ Lbf,
    const _Float16* __restrict__ pwp, const float* __restrict__ pb,
    const float* __restrict__ gb_out,
    float* __restrict__ wcum, _Float16* __restrict__ ctxo,
    float* __restrict__ out, int b, int step, int tid) {
  const _Float16* hb4 = h1 + b * 4;  // index with ((k>>2)<<7) + (k&3)
  if (tid < TIN + KSZ - 1) {
    int tt = tid - 15;
    A->wl[tid] = (tt >= 0 && tt < TIN) ? wcum[b * TIN + tt] : 0.f;
  }
  {  // qp partials: thread (a, kq)
    int a = tid & 127, kq = tid >> 7;
    float s = 0.f;
    const _Float16* qr = qwT + a * 1024 + kq * 256;
    for (int kk = 0; kk < 256; kk += 2) {
      int k = kq * 256 + kk;
      h2 hv = *(const h2*)(hb4 + ((k >> 2) << 7) + (k & 3));
      s = d2(hv, *(const h2*)(qr + kk), s);
    }
    A->qpart[kq * AA + a] = s;
  }
  __syncthreads();
  if (tid < AA)
    A->qp[tid] = A->qpart[tid] + A->qpart[AA + tid] + A->qpart[2 * AA + tid] +
                 A->qpart[3 * AA + tid] + qb[tid];
  __syncthreads();
  {  // energies
    int t = tid & 255, ah = tid >> 8;
    float e = (ah == 0) ? vb[0] : 0.f;
    const _Float16* keyrow = keys16 + (b * TIN + t) * AA;
    for (int c2 = ah * 64; c2 < ah * 64 + 64; c2 += 32) {
      float l32[32];
#pragma unroll
      for (int aa = 0; aa < 32; ++aa) l32[aa] = Lbf[c2 + aa];
      for (int kk = 0; kk < KSZ; ++kk) {
        float wk = A->wl[t + kk];
        const float* Mr = Mf + kk * AA + c2;
#pragma unroll
        for (int aa = 0; aa < 32; ++aa) l32[aa] = fmaf(wk, Mr[aa], l32[aa]);
      }
#pragma unroll
      for (int aa = 0; aa < 32; ++aa) {
        float u = fast_tanh(A->qp[c2 + aa] + (float)keyrow[c2 + aa] + l32[aa]);
        e = fmaf(u, vw[c2 + aa], e);
      }
    }
    A->epart[ah * TIN + t] = e;
  }
  __syncthreads();
  float e = 0.f;
  if (tid < TIN) { e = A->epart[tid] + A->epart[TIN + tid]; A->red[tid] = e; }
  __syncthreads();
  for (int s = 128; s > 0; s >>= 1) {
    if (tid < s) A->red[tid] = fmaxf(A->red[tid], A->red[tid + s]);
    __syncthreads();
  }
  float mx = A->red[0];
  __syncthreads();
  float pp = 0.f;
  if (tid < TIN) { pp = __expf(e - mx); A->red[tid] = pp; }
  __syncthreads();
  for (int s = 128; s > 0; s >>= 1) {
    if (tid < s) A->red[tid] += A->red[tid + s];
    __syncthreads();
  }
  if (tid < TIN) {
    float w = pp / A->red[0];
    A->wsm[tid] = w;
    wcum[b * TIN + tid] += w;
    out[1036800 + (size_t)b * TOUT * TIN + step * TIN + tid] = w;
  }
  __syncthreads();
  {  // ctx = w @ memory ; write k4-blocked ctx
    float s = 0.f;
    const _Float16* mb_ = mem16 + (size_t)b * TIN * EE + tid;
    for (int k = 0; k < TIN; ++k) s = fmaf(A->wsm[k], (float)mb_[k * EE], s);
    A->ctxl[tid] = s;
    ctxo[(tid >> 2) * 128 + b * 4 + (tid & 3)] = (_Float16)s;
  }
  __syncthreads();
  {  // mel(80)+gate(1): xo=[h1,ctx], K=1536 split 4x384; pwp lanes-contiguous
    int kq = tid >> 7, oo = tid & 127;
    float s = 0.f;
    if (oo < 81) {
      int k0 = kq * 384;
      for (int k = k0; k < k0 + 384; ++k) {
        float xo = (k < DD) ? (float)hb4[((k >> 2) << 7) + (k & 3)] : A->ctxl[k - DD];
        s = fmaf(xo, (float)pwp[k * 128 + oo], s);
      }
    }
    A->pred[tid] = s;
  }
  __syncthreads();
  if (tid < 81) {
    float s = A->pred[tid] + A->pred[128 + tid] + A->pred[256 + tid] + A->pred[384 + tid];
    if (tid < 80)
      out[(size_t)b * TOUT * NMEL + step * NMEL + tid] = s + pb[tid];
    else
      out[1024000 + b * TOUT + step] = s + gb_out[0];
  }
}

__global__ __launch_bounds__(512) void k_decoder(
    const _Float16* __restrict__ mem16, const _Float16* __restrict__ px,
    const _Float16* __restrict__ keys16, const _Float16* __restrict__ Wstage,
    const float* __restrict__ l0b, const float* __restrict__ l1b,
    const _Float16* __restrict__ qwT, const float* __restrict__ qb,
    const float* __restrict__ vw, const float* __restrict__ vb,
    const float* __restrict__ Mf, const float* __restrict__ Lbf,
    const _Float16* __restrict__ pwp, const float* __restrict__ pb,
    const float* __restrict__ gb_out,
    char* state, float* out) {
  extern __shared__ char smem[];
  _Float16* Wl = (_Float16*)smem;                 // 139,392
  float* zred  = (float*)(smem + 139392);         // 8,704 (union with AttnS 11,896)
  AttnS* A     = (AttnS*)(smem + 139392);
  float* zfull = (float*)(smem + 151424);         // 2,176
  float* cst   = (float*)(smem + 153664);         // 1,024
  float* gb    = (float*)(smem + 154688);         // 128

  _Float16* h0b[2] = {(_Float16*)state, (_Float16*)(state + 65536)};
  _Float16* h1b[2] = {(_Float16*)(state + 131072), (_Float16*)(state + 196608)};
  _Float16* ctxb[2] = {(_Float16*)(state + 262144), (_Float16*)(state + 294912)};
  float* wcum = (float*)(state + 327680);
  int* bar = (int*)(state + 360448);

  const int B = blockIdx.x, tid = threadIdx.x;

  {  // load this block's weight slice into LDS
    const float4* src = (const float4*)(Wstage + (size_t)B * 16 * KP);
    float4* dst = (float4*)Wl;
    for (int i = tid; i < 16 * KP * 2 / 16; i += 512) dst[i] = src[i];
  }
  if (tid < 256) cst[tid] = 0.f;
  if (tid < 32) {
    int c = tid & 15;
    const float* bb = (tid < 16) ? l0b : l1b;
    gb[tid] = bb[(c & 3) * 1024 + B * 4 + (c >> 2)];
  }
  __syncthreads();

  for (int t = 0; t < TOUT; ++t) {
    const int p = t & 1, q = p ^ 1;
    lstm_phase<1792, 448, 0>(Wl, zred, zfull, cst, gb,
                             px + (size_t)t * 8192, 256,
                             ctxb[q], h0b[q], h0b[p], B, tid);
    gbar(bar, 3 * t + 0, tid);
    lstm_phase<2560, 640, 1792>(Wl, zred, zfull, cst + 128, gb + 16,
                                h0b[p], 1024,
                                ctxb[q], h1b[q], h1b[p], B, tid);
    gbar(bar, 3 * t + 1, tid);
    if (B < BB)
      attn_phase(A, mem16, keys16, h1b[p], qwT, qb, vw, vb, Mf, Lbf,
                 pwp, pb, gb_out, wcum, ctxb[p], out, B, t, tid);
    gbar(bar, 3 * t + 2, tid);
  }
}

// ---------------- host ----------------
extern "C" void kernel_launch(void* const* d_in, const int* in_sizes, int n_in,
                              void* d_out, int out_size, void* d_ws, size_t ws_size,
                              hipStream_t stream) {
  const float* memory  = (const float*)d_in[0];
  const float* targets = (const float*)d_in[1];
  const float* p1w = (const float*)d_in[3];
  const float* p1b = (const float*)d_in[4];
  const float* p2w = (const float*)d_in[5];
  const float* p2b = (const float*)d_in[6];
  const float* l0k = (const float*)d_in[7];
  const float* l0r = (const float*)d_in[8];
  const float* l0b = (const float*)d_in[9];
  const float* l1k = (const float*)d_in[10];
  const float* l1r = (const float*)d_in[11];
  const float* l1b = (const float*)d_in[12];
  const float* qw  = (const float*)d_in[13];
  const float* qb  = (const float*)d_in[14];
  const float* mw  = (const float*)d_in[15];
  const float* mb  = (const float*)d_in[16];
  const float* vw  = (const float*)d_in[17];
  const float* vb  = (const float*)d_in[18];
  const float* cw  = (const float*)d_in[19];
  const float* cb  = (const float*)d_in[20];
  const float* ldw = (const float*)d_in[21];
  const float* ldb = (const float*)d_in[22];
  const float* pw  = (const float*)d_in[23];
  const float* pb  = (const float*)d_in[24];
  const float* gw  = (const float*)d_in[25];
  const float* gb  = (const float*)d_in[26];

  char* W = (char*)d_ws;
  _Float16* px16   = (_Float16*)(W + 0);           //  6,553,600 B
  _Float16* keys16 = (_Float16*)(W + 6553600);     //  2,097,152
  _Float16* mem16  = (_Float16*)(W + 8650752);     //  8,388,608
  _Float16* qwT16  = (_Float16*)(W + 17039360);    //    262,144
  _Float16* pwp    = (_Float16*)(W + 17301504);    //    393,216
  float*    Mf     = (float*)   (W + 17694720);    //     15,872
  float*    Lbf    = (float*)   (W + 17710592);    //        512
  _Float16* Wstage = (_Float16*)(W + 17711104);    // 35,684,352
  char*     state  =             W + 53395456;     //    364,544
  float* out = (float*)d_out;

  // zero recurrent state + barrier counters (ws re-poisoned before every call)
  hipMemsetAsync(state, 0, 364544, stream);

  k_prenet<<<TOUT * BB, PRE, 0, stream>>>(targets, p1w, p1b, p2w, p2b, px16);
  k_keys<<<BB * TIN, AA, 0, stream>>>(memory, mw, mb, keys16);
  k_locM<<<1, AA, 0, stream>>>(cw, cb, ldw, ldb, Mf, Lbf);
  k_cast<<<(4194304 + 255) / 256, 256, 0, stream>>>(memory, mem16, 4194304);
  k_castT<<<(131072 + 255) / 256, 256, 0, stream>>>(qw, qwT16);
  k_permP<<<768, 256, 0, stream>>>(pw, gw, pwp);
  // weight slices: rows [l0k 0..767 | l0r 768..1791 | l1k 1792..3327 | l1r 3328..4351]
  k_perm<<<(768 * 1024 + 255) / 256, 256, 0, stream>>>(l0k, Wstage, 768, 0);
  k_perm<<<(1024 * 1024 + 255) / 256, 256, 0, stream>>>(l0r, Wstage, 1024, 768);
  k_perm<<<(1536 * 1024 + 255) / 256, 256, 0, stream>>>(l1k, Wstage, 1536, 1792);
  k_perm<<<(1024 * 1024 + 255) / 256, 256, 0, stream>>>(l1r, Wstage, 1024, 1792 + 1536);

  void* args[] = {(void*)&mem16, (void*)&px16, (void*)&keys16, (void*)&Wstage,
                  (void*)&l0b, (void*)&l1b, (void*)&qwT16, (void*)&qb,
                  (void*)&vw, (void*)&vb, (void*)&Mf, (void*)&Lbf,
                  (void*)&pwp, (void*)&pb, (void*)&gb,
                  (void*)&state, (void*)&out};
  hipLaunchCooperativeKernel((const void*)k_decoder, dim3(256), dim3(512), args,
                             154816, stream);
}

// Round 8
// 62900.787 us; speedup vs baseline: 1.0580x; 1.0580x over previous
//
#include <hip/hip_runtime.h>
#include <math.h>

#define BB 32
#define TIN 256
#define TOUT 400
#define EE 512
#define AA 128
#define KSZ 31
#define PRE 256
#define DD 1024
#define NMEL 80
#define NF 32
#define KP 4360          // padded K-rows per LDS weight column (16B-aligned rows)

typedef _Float16 h2 __attribute__((ext_vector_type(2)));
typedef _Float16 h8 __attribute__((ext_vector_type(8)));

__device__ __forceinline__ float fast_sigmoid(float x) { return 1.f / (1.f + __expf(-x)); }
__device__ __forceinline__ float fast_tanh(float x) {
  float ax = fabsf(x);
  float e = __expf(fminf(2.f * ax, 40.f));
  return copysignf((e - 1.f) / (e + 1.f), x);
}
__device__ __forceinline__ float d2(h2 a, h2 b, float c) {
#if __has_builtin(__builtin_amdgcn_fdot2)
  return __builtin_amdgcn_fdot2(a, b, c, false);
#else
  return fmaf((float)a[0], (float)b[0], fmaf((float)a[1], (float)b[1], c));
#endif
}
__device__ __forceinline__ float dot8(h8 a, h8 b, float c) {
  c = d2((h2){a[0], a[1]}, (h2){b[0], b[1]}, c);
  c = d2((h2){a[2], a[3]}, (h2){b[2], b[3]}, c);
  c = d2((h2){a[4], a[5]}, (h2){b[4], b[5]}, c);
  c = d2((h2){a[6], a[7]}, (h2){b[6], b[7]}, c);
  return c;
}

// ---------------- setup kernels ----------------
// px flat: px[t][b][256]
__global__ void k_prenet(const float* __restrict__ targets,
                         const float* __restrict__ w1, const float* __restrict__ b1,
                         const float* __restrict__ w2, const float* __restrict__ b2,
                         _Float16* __restrict__ px) {
  int t = blockIdx.x >> 5, b = blockIdx.x & 31, j = threadIdx.x;
  __shared__ float din[NMEL];
  __shared__ float hl[PRE];
  if (j < NMEL) din[j] = (t == 0) ? 0.f : targets[(b * TOUT + (t - 1)) * NMEL + j];
  __syncthreads();
  float s = b1[j];
#pragma unroll
  for (int k = 0; k < NMEL; ++k) s = fmaf(din[k], w1[k * PRE + j], s);
  hl[j] = fmaxf(s, 0.f);
  __syncthreads();
  float s2 = b2[j];
  for (int k = 0; k < PRE; ++k) s2 = fmaf(hl[k], w2[k * PRE + j], s2);
  px[(size_t)t * 8192 + b * 256 + j] = (_Float16)fmaxf(s2, 0.f);
}

__global__ void k_keys(const float* __restrict__ memory, const float* __restrict__ mw,
                       const float* __restrict__ mb, _Float16* __restrict__ keys) {
  int row = blockIdx.x, a = threadIdx.x;
  __shared__ float mrow[EE];
  for (int i = a; i < EE; i += AA) mrow[i] = memory[row * EE + i];
  __syncthreads();
  float s = mb[a];
  for (int k = 0; k < EE; ++k) s = fmaf(mrow[k], mw[k * AA + a], s);
  keys[row * AA + a] = (_Float16)s;
}

__global__ void k_locM(const float* __restrict__ cw, const float* __restrict__ cb,
                       const float* __restrict__ ldw, const float* __restrict__ ldb,
                       float* __restrict__ M, float* __restrict__ Lb) {
  int a = threadIdx.x;
  for (int kk = 0; kk < KSZ; ++kk) {
    float s = 0.f;
    for (int f = 0; f < NF; ++f) s = fmaf(cw[kk * NF + f], ldw[f * AA + a], s);
    M[kk * AA + a] = s;
  }
  float s = ldb[a];
  for (int f = 0; f < NF; ++f) s = fmaf(cb[f], ldw[f * AA + a], s);
  Lb[a] = s;
}

// qw [1024][128] -> qwT [128][1024] fp16
__global__ void k_castT(const float* __restrict__ qw, _Float16* __restrict__ qwT) {
  int i = blockIdx.x * 256 + threadIdx.x;  // 131072
  int k = i >> 7, a = i & 127;
  qwT[a * 1024 + k] = (_Float16)qw[k * 128 + a];
}

// memory [b][t][e] -> memT [b][e][t] fp16, tiled transpose
__global__ void k_memT(const float* __restrict__ mem, _Float16* __restrict__ memT) {
  __shared__ _Float16 tile[32][33];
  int b = blockIdx.x >> 7;
  int tt = (blockIdx.x >> 4) & 7;
  int ee = blockIdx.x & 15;
  int r = threadIdx.x >> 5, cc = threadIdx.x & 31;
#pragma unroll
  for (int i = 0; i < 4; ++i) {
    int t = tt * 32 + r + i * 8, e = ee * 32 + cc;
    tile[r + i * 8][cc] = (_Float16)mem[((size_t)b * 256 + t) * 512 + e];
  }
  __syncthreads();
#pragma unroll
  for (int i = 0; i < 4; ++i) {
    int e = ee * 32 + r + i * 8, t = tt * 32 + cc;
    memT[((size_t)b * 512 + e) * 256 + t] = tile[cc][r + i * 8];
  }
}

// proj+gate weights transposed: pwpT[o][k], o<80 = mel col o, o=80 = gate
__global__ void k_permP(const float* __restrict__ pw, const float* __restrict__ gw,
                        _Float16* __restrict__ pwpT) {
  int i = blockIdx.x * 256 + threadIdx.x;  // 128*1536
  int o = i / 1536, k = i % 1536;
  float v = (o < 80) ? pw[k * 80 + o] : ((o == 80) ? gw[k] : 0.f);
  pwpT[i] = (_Float16)v;
}

// gate-interleave + per-block-slice permute: col p=4j+g; block B=j>>2 owns 16
// cols; c=4*(j&3)+g; dst[(B*16+c)*KP + row_off + k]
__global__ void k_perm(const float* __restrict__ src, _Float16* __restrict__ dst,
                       int rows, int row_off) {
  int idx = blockIdx.x * 256 + threadIdx.x;
  int k = idx >> 10, j = idx & 1023;
  if (k >= rows) return;
  const float* s = src + (size_t)k * 4096 + j;
  int base = (j >> 2) * 16 + 4 * (j & 3);
#pragma unroll
  for (int g = 0; g < 4; ++g)
    dst[(size_t)(base + g) * KP + row_off + k] = (_Float16)s[g * 1024];
}

// ---------------- persistent decoder ----------------
struct AttnS {               // 10,360 B, lives in the 12 KB union region
  _Float16 ctx16[EE];        // 16B-aligned at struct base
  _Float16 wsm16[TIN];
  float wl[TIN + KSZ - 1];
  float qpart[512];
  float qp[AA];
  float red[TIN];
  float epart[512];
  float pred[512];
};

// two-level grid barrier: 8 group counters -> epoch -> 8 doors
__device__ __forceinline__ void gbar(int* bar, int ord, int tid) {
  __syncthreads();
  if (tid == 0) {
    __builtin_amdgcn_fence(__ATOMIC_RELEASE, "agent");
    int g = blockIdx.x & 7;
    int old = __hip_atomic_fetch_add(bar + g * 16, 1, __ATOMIC_RELAXED,
                                     __HIP_MEMORY_SCOPE_AGENT);
    if ((old & 31) == 31) {
      int e = __hip_atomic_fetch_add(bar + 128, 1, __ATOMIC_RELAXED,
                                     __HIP_MEMORY_SCOPE_AGENT);
      if (e == 8 * ord + 7) {
#pragma unroll
        for (int d = 0; d < 8; ++d)
          __hip_atomic_store(bar + 144 + d * 16, ord + 1, __ATOMIC_RELAXED,
                             __HIP_MEMORY_SCOPE_AGENT);
      }
    }
    while (__hip_atomic_load(bar + 144 + g * 16, __ATOMIC_RELAXED,
                             __HIP_MEMORY_SCOPE_AGENT) < ord + 1)
      __builtin_amdgcn_s_sleep(4);
    __builtin_amdgcn_fence(__ATOMIC_ACQUIRE, "agent");
  }
  __syncthreads();
}

// LSTM phase: thread (c in 16, b in 32) computes z[c][b] over full K.
// x flat [b][K] fp16, read as 16B h8 with 2-chunk register prefetch (round-7
// showed latency-bound narrow loads: VALUBusy 10%, all pipes idle).
template <int KT, int WOFF, int L0, int L01, int RL0>
__device__ __forceinline__ void lstm_phase(
    const _Float16* __restrict__ Wl, float* __restrict__ zfull,
    float* __restrict__ cstL, const float* __restrict__ gbl,
    const _Float16* __restrict__ s0, const _Float16* __restrict__ s1,
    const _Float16* __restrict__ s2, _Float16* __restrict__ hout,
    int B, int tid) {
  constexpr int NCH = KT / 64;
  const int c = tid & 15, b = tid >> 4;
  const _Float16* p0 = s0 + b * RL0;
  const _Float16* p1 = s1 + b * 512;
  const _Float16* p2 = s2 + b * 1024;
  const _Float16* Wrow = Wl + c * KP + WOFF;
  float acc = 0.f;
  h8 xA[8], xB[8];
  auto ldch = [&](int ch, h8* dst) {
    int kk = ch * 64;
    const _Float16* xp = (kk < L0) ? p0 + kk
                        : (kk < L01) ? p1 + (kk - L0) : p2 + (kk - L01);
#pragma unroll
    for (int i = 0; i < 8; ++i) dst[i] = *(const h8*)(xp + i * 8);
  };
  ldch(0, xA);
  ldch(1, xB);
#pragma unroll 4
  for (int ch = 0; ch < NCH; ++ch) {
    h8 xC[8];
    int nx = ch + 2 < NCH ? ch + 2 : NCH - 1;
    ldch(nx, xC);
    const _Float16* wr = Wrow + ch * 64;
#pragma unroll
    for (int i = 0; i < 8; ++i) {
      h8 w = *(const h8*)(wr + i * 8);
      acc = dot8(w, xA[i], acc);
    }
#pragma unroll
    for (int i = 0; i < 8; ++i) { xA[i] = xB[i]; xB[i] = xC[i]; }
  }
  zfull[b * 17 + c] = acc;
  __syncthreads();
  if (tid < 128) {
    int jj = tid >> 5, bb = tid & 31;
    float zi = zfull[bb * 17 + 4 * jj + 0] + gbl[4 * jj + 0];
    float zf = zfull[bb * 17 + 4 * jj + 1] + gbl[4 * jj + 1];
    float zg = zfull[bb * 17 + 4 * jj + 2] + gbl[4 * jj + 2];
    float zo = zfull[bb * 17 + 4 * jj + 3] + gbl[4 * jj + 3];
    float ig = fast_sigmoid(zi), fg = fast_sigmoid(zf);
    float gg = fast_tanh(zg), og = fast_sigmoid(zo);
    float cn = fg * cstL[jj * 32 + bb] + ig * gg;
    cstL[jj * 32 + bb] = cn;
    hout[bb * 1024 + B * 4 + jj] = (_Float16)(og * fast_tanh(cn));
  }
}

__device__ __forceinline__ void attn_phase(
    AttnS* A, const _Float16* __restrict__ memT, const _Float16* __restrict__ keys16,
    const _Float16* __restrict__ h1,
    const _Float16* __restrict__ qwT, const float* __restrict__ qb,
    const float* __restrict__ vw, const float* __restrict__ vb,
    const float* __restrict__ Mf, const float* __restrict__ Lbf,
    const _Float16* __restrict__ pwpT, const float* __restrict__ pb,
    const float* __restrict__ gb_out,
    float* __restrict__ wcum, _Float16* __restrict__ ctxo,
    float* __restrict__ out, int b, int step, int tid) {
  if (tid < TIN + KSZ - 1) {
    int tt = tid - 15;
    A->wl[tid] = (tt >= 0 && tt < TIN) ? wcum[b * TIN + tt] : 0.f;
  }
  {  // qp partials: thread (a, kq), h8 vector dots
    int a = tid & 127, kq = tid >> 7;
    const _Float16* hr = h1 + b * DD + kq * 256;
    const _Float16* qr = qwT + a * 1024 + kq * 256;
    float s = 0.f;
#pragma unroll 8
    for (int i = 0; i < 32; ++i)
      s = dot8(*(const h8*)(hr + i * 8), *(const h8*)(qr + i * 8), s);
    A->qpart[kq * AA + a] = s;
  }
  __syncthreads();
  if (tid < AA)
    A->qp[tid] = A->qpart[tid] + A->qpart[AA + tid] + A->qpart[2 * AA + tid] +
                 A->qpart[3 * AA + tid] + qb[tid];
  __syncthreads();
  {  // energies: thread (t, ah); keys via h8, Mf via float4 broadcast
    int t = tid & 255, ah = tid >> 8;
    const _Float16* keyrow = keys16 + ((size_t)(b * TIN + t)) * AA + ah * 64;
    h8 kv[8];
#pragma unroll
    for (int i = 0; i < 8; ++i) kv[i] = *(const h8*)(keyrow + i * 8);
    float e = (ah == 0) ? vb[0] : 0.f;
#pragma unroll
    for (int half = 0; half < 2; ++half) {
      int c2 = ah * 64 + half * 32;
      float l32[32];
      const float4* Lb4 = (const float4*)(Lbf + c2);
#pragma unroll
      for (int q = 0; q < 8; ++q) {
        float4 v = Lb4[q];
        l32[4 * q] = v.x; l32[4 * q + 1] = v.y; l32[4 * q + 2] = v.z; l32[4 * q + 3] = v.w;
      }
      for (int kk = 0; kk < KSZ; ++kk) {
        float wk = A->wl[t + kk];
        const float4* Mr = (const float4*)(Mf + kk * AA + c2);
#pragma unroll
        for (int q = 0; q < 8; ++q) {
          float4 m = Mr[q];
          l32[4 * q]     = fmaf(wk, m.x, l32[4 * q]);
          l32[4 * q + 1] = fmaf(wk, m.y, l32[4 * q + 1]);
          l32[4 * q + 2] = fmaf(wk, m.z, l32[4 * q + 2]);
          l32[4 * q + 3] = fmaf(wk, m.w, l32[4 * q + 3]);
        }
      }
#pragma unroll
      for (int aa = 0; aa < 32; ++aa) {
        float kf = (float)kv[(half * 32 + aa) >> 3][(half * 32 + aa) & 7];
        float u = fast_tanh(A->qp[c2 + aa] + kf + l32[aa]);
        e = fmaf(u, vw[c2 + aa], e);
      }
    }
    A->epart[ah * TIN + t] = e;
  }
  __syncthreads();
  float e = 0.f;
  if (tid < TIN) { e = A->epart[tid] + A->epart[TIN + tid]; A->red[tid] = e; }
  __syncthreads();
  for (int s = 128; s > 0; s >>= 1) {
    if (tid < s) A->red[tid] = fmaxf(A->red[tid], A->red[tid + s]);
    __syncthreads();
  }
  float mx = A->red[0];
  __syncthreads();
  float pp = 0.f;
  if (tid < TIN) { pp = __expf(e - mx); A->red[tid] = pp; }
  __syncthreads();
  for (int s = 128; s > 0; s >>= 1) {
    if (tid < s) A->red[tid] += A->red[tid + s];
    __syncthreads();
  }
  if (tid < TIN) {
    float w = pp / A->red[0];
    A->wsm16[tid] = (_Float16)w;
    wcum[b * TIN + tid] += w;
    out[1036800 + (size_t)b * TOUT * TIN + step * TIN + tid] = w;
  }
  __syncthreads();
  {  // ctx = w @ memory via memT rows (contiguous h8)
    const _Float16* mr = memT + ((size_t)(b * EE + tid)) * TIN;
    float s = 0.f;
#pragma unroll 8
    for (int i = 0; i < 32; ++i)
      s = dot8(*(const h8*)(A->wsm16 + i * 8), *(const h8*)(mr + i * 8), s);
    A->ctx16[tid] = (_Float16)s;
    ctxo[b * EE + tid] = (_Float16)s;
  }
  __syncthreads();
  {  // mel(80)+gate(1): xo=[h1,ctx16], pwpT rows contiguous
    int kq = tid >> 7, oo = tid & 127;
    if (oo < 81) {
      const _Float16* pr = pwpT + oo * 1536 + kq * 384;
      const _Float16* hr = h1 + b * DD;
      float s = 0.f;
#pragma unroll 4
      for (int kk = 0; kk < 384; kk += 8) {
        int k = kq * 384 + kk;
        h8 xv = (k < DD) ? *(const h8*)(hr + k) : *(const h8*)(A->ctx16 + (k - DD));
        s = dot8(xv, *(const h8*)(pr + kk), s);
      }
      A->pred[tid] = s;
    }
  }
  __syncthreads();
  if (tid < 81) {
    float s = A->pred[tid] + A->pred[128 + tid] + A->pred[256 + tid] + A->pred[384 + tid];
    if (tid < 80)
      out[(size_t)b * TOUT * NMEL + step * NMEL + tid] = s + pb[tid];
    else
      out[1024000 + b * TOUT + step] = s + gb_out[0];
  }
}

__global__ __launch_bounds__(512, 2) void k_decoder(
    const _Float16* __restrict__ memT, const _Float16* __restrict__ px,
    const _Float16* __restrict__ keys16, const _Float16* __restrict__ Wstage,
    const float* __restrict__ l0b, const float* __restrict__ l1b,
    const _Float16* __restrict__ qwT, const float* __restrict__ qb,
    const float* __restrict__ vw, const float* __restrict__ vb,
    const float* __restrict__ Mf, const float* __restrict__ Lbf,
    const _Float16* __restrict__ pwpT, const float* __restrict__ pb,
    const float* __restrict__ gb_out,
    char* state, float* out) {
  extern __shared__ char smem[];
  _Float16* Wl = (_Float16*)smem;                 // 16*KP*2 = 139,520
  float* zfull = (float*)(smem + 139520);         // union with AttnS (12 KB)
  AttnS* A     = (AttnS*)(smem + 139520);
  float* cst   = (float*)(smem + 151808);         // 1,024
  float* gb    = (float*)(smem + 152832);         // 128

  _Float16* h0b[2] = {(_Float16*)state, (_Float16*)(state + 65536)};
  _Float16* h1b[2] = {(_Float16*)(state + 131072), (_Float16*)(state + 196608)};
  _Float16* ctxb[2] = {(_Float16*)(state + 262144), (_Float16*)(state + 294912)};
  float* wcum = (float*)(state + 327680);
  int* bar = (int*)(state + 360448);

  const int B = blockIdx.x, tid = threadIdx.x;

  {  // load this block's weight slice into LDS
    const float4* src = (const float4*)(Wstage + (size_t)B * 16 * KP);
    float4* dst = (float4*)Wl;
    for (int i = tid; i < 16 * KP * 2 / 16; i += 512) dst[i] = src[i];
  }
  if (tid < 256) cst[tid] = 0.f;
  if (tid < 32) {
    int c = tid & 15;
    const float* bb = (tid < 16) ? l0b : l1b;
    gb[tid] = bb[(c & 3) * 1024 + B * 4 + (c >> 2)];
  }
  __syncthreads();

  for (int t = 0; t < TOUT; ++t) {
    const int p = t & 1, q = p ^ 1;
    lstm_phase<1792, 0, 256, 768, 256>(Wl, zfull, cst, gb,
                                       px + (size_t)t * 8192, ctxb[q], h0b[q],
                                       h0b[p], B, tid);
    gbar(bar, 3 * t + 0, tid);
    lstm_phase<2560, 1792, 1024, 1536, 1024>(Wl, zfull, cst + 128, gb + 16,
                                             h0b[p], ctxb[q], h1b[q],
                                             h1b[p], B, tid);
    gbar(bar, 3 * t + 1, tid);
    if (B < BB)
      attn_phase(A, memT, keys16, h1b[p], qwT, qb, vw, vb, Mf, Lbf,
                 pwpT, pb, gb_out, wcum, ctxb[p], out, B, t, tid);
    gbar(bar, 3 * t + 2, tid);
  }
}

// ---------------- host ----------------
extern "C" void kernel_launch(void* const* d_in, const int* in_sizes, int n_in,
                              void* d_out, int out_size, void* d_ws, size_t ws_size,
                              hipStream_t stream) {
  const float* memory  = (const float*)d_in[0];
  const float* targets = (const float*)d_in[1];
  const float* p1w = (const float*)d_in[3];
  const float* p1b = (const float*)d_in[4];
  const float* p2w = (const float*)d_in[5];
  const float* p2b = (const float*)d_in[6];
  const float* l0k = (const float*)d_in[7];
  const float* l0r = (const float*)d_in[8];
  const float* l0b = (const float*)d_in[9];
  const float* l1k = (const float*)d_in[10];
  const float* l1r = (const float*)d_in[11];
  const float* l1b = (const float*)d_in[12];
  const float* qw  = (const float*)d_in[13];
  const float* qb  = (const float*)d_in[14];
  const float* mw  = (const float*)d_in[15];
  const float* mb  = (const float*)d_in[16];
  const float* vw  = (const float*)d_in[17];
  const float* vb  = (const float*)d_in[18];
  const float* cw  = (const float*)d_in[19];
  const float* cb  = (const float*)d_in[20];
  const float* ldw = (const float*)d_in[21];
  const float* ldb = (const float*)d_in[22];
  const float* pw  = (const float*)d_in[23];
  const float* pb  = (const float*)d_in[24];
  const float* gw  = (const float*)d_in[25];
  const float* gb  = (const float*)d_in[26];

  char* W = (char*)d_ws;
  _Float16* px16   = (_Float16*)(W + 0);           //  6,553,600
  _Float16* keys16 = (_Float16*)(W + 6553600);     //  2,097,152
  _Float16* memT16 = (_Float16*)(W + 8650752);     //  8,388,608
  _Float16* qwT16  = (_Float16*)(W + 17039360);    //    262,144
  _Float16* pwpT   = (_Float16*)(W + 17301504);    //    393,216
  float*    Mf     = (float*)   (W + 17694720);    //     15,872
  float*    Lbf    = (float*)   (W + 17710592);    //        512
  _Float16* Wstage = (_Float16*)(W + 17711104);    // 35,717,120
  char*     state  =             W + 53428224;     //    361,472
  float* out = (float*)d_out;

  // zero recurrent state + barrier counters (ws re-poisoned before every call)
  hipMemsetAsync(state, 0, 361472, stream);

  k_prenet<<<TOUT * BB, PRE, 0, stream>>>(targets, p1w, p1b, p2w, p2b, px16);
  k_keys<<<BB * TIN, AA, 0, stream>>>(memory, mw, mb, keys16);
  k_locM<<<1, AA, 0, stream>>>(cw, cb, ldw, ldb, Mf, Lbf);
  k_memT<<<4096, 256, 0, stream>>>(memory, memT16);
  k_castT<<<(131072 + 255) / 256, 256, 0, stream>>>(qw, qwT16);
  k_permP<<<768, 256, 0, stream>>>(pw, gw, pwpT);
  // weight slices: rows [l0k 0..767 | l0r 768..1791 | l1k 1792..3327 | l1r 3328..4351]
  k_perm<<<(768 * 1024 + 255) / 256, 256, 0, stream>>>(l0k, Wstage, 768, 0);
  k_perm<<<(1024 * 1024 + 255) / 256, 256, 0, stream>>>(l0r, Wstage, 1024, 768);
  k_perm<<<(1536 * 1024 + 255) / 256, 256, 0, stream>>>(l1k, Wstage, 1536, 1792);
  k_perm<<<(1024 * 1024 + 255) / 256, 256, 0, stream>>>(l1r, Wstage, 1024, 1792 + 1536);

  void* args[] = {(void*)&memT16, (void*)&px16, (void*)&keys16, (void*)&Wstage,
                  (void*)&l0b, (void*)&l1b, (void*)&qwT16, (void*)&qb,
                  (void*)&vw, (void*)&vb, (void*)&Mf, (void*)&Lbf,
                  (void*)&pwpT, (void*)&pb, (void*)&gb,
                  (void*)&state, (void*)&out};
  hipLaunchCooperativeKernel((const void*)k_decoder, dim3(256), dim3(512), args,
                             152960, stream);
}

// Round 9
// 59254.895 us; speedup vs baseline: 1.1231x; 1.0615x over previous
//
#include <hip/hip_runtime.h>
#include <math.h>

#define BB 32
#define TIN 256
#define TOUT 400
#define EE 512
#define AA 128
#define KSZ 31
#define PRE 256
#define DD 1024
#define NMEL 80
#define NF 32
#define KP 4360          // padded K-rows per LDS weight column (16B-aligned rows)

typedef _Float16 h2 __attribute__((ext_vector_type(2)));
typedef _Float16 h4 __attribute__((ext_vector_type(4)));
typedef _Float16 h8 __attribute__((ext_vector_type(8)));

__device__ __forceinline__ float fast_sigmoid(float x) { return 1.f / (1.f + __expf(-x)); }
__device__ __forceinline__ float fast_tanh(float x) {
  float ax = fabsf(x);
  float e = __expf(fminf(2.f * ax, 40.f));
  return copysignf((e - 1.f) / (e + 1.f), x);
}
__device__ __forceinline__ float d2(h2 a, h2 b, float c) {
#if __has_builtin(__builtin_amdgcn_fdot2)
  return __builtin_amdgcn_fdot2(a, b, c, false);
#else
  return fmaf((float)a[0], (float)b[0], fmaf((float)a[1], (float)b[1], c));
#endif
}
__device__ __forceinline__ float dot8(h8 a, h8 b, float c) {
  c = d2((h2){a[0], a[1]}, (h2){b[0], b[1]}, c);
  c = d2((h2){a[2], a[3]}, (h2){b[2], b[3]}, c);
  c = d2((h2){a[4], a[5]}, (h2){b[4], b[5]}, c);
  c = d2((h2){a[6], a[7]}, (h2){b[6], b[7]}, c);
  return c;
}

// ---- LLC-coherent 8B load/store (sc0 sc1: bypass L1/L2, no fences needed) ----
__device__ __forceinline__ h4 ld_cc8(const _Float16* p) {
  unsigned long long v = __hip_atomic_load((const unsigned long long*)p,
                                           __ATOMIC_RELAXED, __HIP_MEMORY_SCOPE_SYSTEM);
  union { unsigned long long u; h4 h; } c; c.u = v; return c.h;
}
__device__ __forceinline__ void st_cc8(_Float16* p, h4 x) {
  union { unsigned long long u; h4 h; } c; c.h = x;
  __hip_atomic_store((unsigned long long*)p, c.u, __ATOMIC_RELAXED,
                     __HIP_MEMORY_SCOPE_SYSTEM);
}

// ---------------- setup kernels ----------------
// px flat: px[t][b][256]  (read-only in decoder -> normal cached loads)
__global__ void k_prenet(const float* __restrict__ targets,
                         const float* __restrict__ w1, const float* __restrict__ b1,
                         const float* __restrict__ w2, const float* __restrict__ b2,
                         _Float16* __restrict__ px) {
  int t = blockIdx.x >> 5, b = blockIdx.x & 31, j = threadIdx.x;
  __shared__ float din[NMEL];
  __shared__ float hl[PRE];
  if (j < NMEL) din[j] = (t == 0) ? 0.f : targets[(b * TOUT + (t - 1)) * NMEL + j];
  __syncthreads();
  float s = b1[j];
#pragma unroll
  for (int k = 0; k < NMEL; ++k) s = fmaf(din[k], w1[k * PRE + j], s);
  hl[j] = fmaxf(s, 0.f);
  __syncthreads();
  float s2 = b2[j];
  for (int k = 0; k < PRE; ++k) s2 = fmaf(hl[k], w2[k * PRE + j], s2);
  px[(size_t)t * 8192 + b * 256 + j] = (_Float16)fmaxf(s2, 0.f);
}

__global__ void k_keys(const float* __restrict__ memory, const float* __restrict__ mw,
                       const float* __restrict__ mb, _Float16* __restrict__ keys) {
  int row = blockIdx.x, a = threadIdx.x;
  __shared__ float mrow[EE];
  for (int i = a; i < EE; i += AA) mrow[i] = memory[row * EE + i];
  __syncthreads();
  float s = mb[a];
  for (int k = 0; k < EE; ++k) s = fmaf(mrow[k], mw[k * AA + a], s);
  keys[row * AA + a] = (_Float16)s;
}

__global__ void k_locM(const float* __restrict__ cw, const float* __restrict__ cb,
                       const float* __restrict__ ldw, const float* __restrict__ ldb,
                       float* __restrict__ M, float* __restrict__ Lb) {
  int a = threadIdx.x;
  for (int kk = 0; kk < KSZ; ++kk) {
    float s = 0.f;
    for (int f = 0; f < NF; ++f) s = fmaf(cw[kk * NF + f], ldw[f * AA + a], s);
    M[kk * AA + a] = s;
  }
  float s = ldb[a];
  for (int f = 0; f < NF; ++f) s = fmaf(cb[f], ldw[f * AA + a], s);
  Lb[a] = s;
}

// qw [1024][128] -> qwT [128][1024] fp16
__global__ void k_castT(const float* __restrict__ qw, _Float16* __restrict__ qwT) {
  int i = blockIdx.x * 256 + threadIdx.x;  // 131072
  int k = i >> 7, a = i & 127;
  qwT[a * 1024 + k] = (_Float16)qw[k * 128 + a];
}

// memory [b][t][e] -> memT [b][e][t] fp16, tiled transpose
__global__ void k_memT(const float* __restrict__ mem, _Float16* __restrict__ memT) {
  __shared__ _Float16 tile[32][33];
  int b = blockIdx.x >> 7;
  int tt = (blockIdx.x >> 4) & 7;
  int ee = blockIdx.x & 15;
  int r = threadIdx.x >> 5, cc = threadIdx.x & 31;
#pragma unroll
  for (int i = 0; i < 4; ++i) {
    int t = tt * 32 + r + i * 8, e = ee * 32 + cc;
    tile[r + i * 8][cc] = (_Float16)mem[((size_t)b * 256 + t) * 512 + e];
  }
  __syncthreads();
#pragma unroll
  for (int i = 0; i < 4; ++i) {
    int e = ee * 32 + r + i * 8, t = tt * 32 + cc;
    memT[((size_t)b * 512 + e) * 256 + t] = tile[cc][r + i * 8];
  }
}

// proj+gate weights transposed: pwpT[o][k], o<80 = mel col o, o=80 = gate
__global__ void k_permP(const float* __restrict__ pw, const float* __restrict__ gw,
                        _Float16* __restrict__ pwpT) {
  int i = blockIdx.x * 256 + threadIdx.x;  // 128*1536
  int o = i / 1536, k = i % 1536;
  float v = (o < 80) ? pw[k * 80 + o] : ((o == 80) ? gw[k] : 0.f);
  pwpT[i] = (_Float16)v;
}

// gate-interleave + per-block-slice permute: col p=4j+g; block B=j>>2 owns 16
// cols; c=4*(j&3)+g; dst[(B*16+c)*KP + row_off + k]
__global__ void k_perm(const float* __restrict__ src, _Float16* __restrict__ dst,
                       int rows, int row_off) {
  int idx = blockIdx.x * 256 + threadIdx.x;
  int k = idx >> 10, j = idx & 1023;
  if (k >= rows) return;
  const float* s = src + (size_t)k * 4096 + j;
  int base = (j >> 2) * 16 + 4 * (j & 3);
#pragma unroll
  for (int g = 0; g < 4; ++g)
    dst[(size_t)(base + g) * KP + row_off + k] = (_Float16)s[g * 1024];
}

// ---------------- persistent decoder ----------------
struct __align__(16) AttnS {
  _Float16 h1l[1024];        // staged h1[b] (cc-loaded once per step)
  _Float16 ctx16[EE];
  _Float16 wsm16[TIN];
  float wl[TIN + KSZ - 1];
  float qpart[512];
  float qp[AA];
  float red[TIN];
  float epart[512];
  float pred[512];
};                           // 12,408 B

// fence-free grid barrier: system-scope relaxed atomics (execute at LLC).
// No agent fences -> no L2 writeback/invalidate (round 6-8's ~40us/barrier).
// __syncthreads on entry drains each wave's vmcnt -> all cc stores visible.
__device__ __forceinline__ void gbar(int* bar, int ord, int tid) {
  __syncthreads();
  if (tid == 0) {
    __builtin_amdgcn_fence(__ATOMIC_RELEASE, "workgroup");  // compiler-order only
    int g = blockIdx.x & 7;
    int old = __hip_atomic_fetch_add(bar + g * 16, 1, __ATOMIC_RELAXED,
                                     __HIP_MEMORY_SCOPE_SYSTEM);
    if ((old & 31) == 31) {
      int e = __hip_atomic_fetch_add(bar + 128, 1, __ATOMIC_RELAXED,
                                     __HIP_MEMORY_SCOPE_SYSTEM);
      if (e == 8 * ord + 7) {
#pragma unroll
        for (int d = 0; d < 8; ++d)
          __hip_atomic_store(bar + 144 + d * 16, ord + 1, __ATOMIC_RELAXED,
                             __HIP_MEMORY_SCOPE_SYSTEM);
      }
    }
    while (__hip_atomic_load(bar + 144 + g * 16, __ATOMIC_RELAXED,
                             __HIP_MEMORY_SCOPE_SYSTEM) < ord + 1)
      __builtin_amdgcn_s_sleep(2);
    __builtin_amdgcn_fence(__ATOMIC_ACQUIRE, "workgroup");  // compiler-order only
  }
  __syncthreads();
}

// LSTM phase: thread (c in 16, b in 32) computes z[c][b] over full K.
// p0 = read-only segment (normal cached h8); p1..p3 = mutable state read via
// ld_cc8 (LLC-coherent). 2-chunk register prefetch, compiler-tracked vmcnt.
template <int KT, int WOFF, int L0, int L01, int L02>
__device__ __forceinline__ void lstm_phase(
    const _Float16* __restrict__ Wl, float* __restrict__ zfull,
    _Float16* __restrict__ hbuf, float* __restrict__ cstL,
    const float* __restrict__ gbl,
    const _Float16* __restrict__ p0, const _Float16* __restrict__ p1,
    const _Float16* __restrict__ p2, const _Float16* __restrict__ p3,
    _Float16* __restrict__ hout, int B, int tid) {
  constexpr int NCH = KT / 64;
  const int c = tid & 15, b = tid >> 4;
  const _Float16* p0b = p0 + b * L0;
  const _Float16* p1b = p1 + b * (L01 - L0);
  const _Float16* p2b = p2 + b * (L02 - L01);
  const _Float16* p3b = p3 + b * (KT - L02);
  const _Float16* Wrow = Wl + c * KP + WOFF;
  float acc = 0.f;
  h4 xA[16], xB[16];
  auto ldch = [&](int ch, h4* dst) {
    const int kk = ch * 64;
    if (L0 > 0 && kk < L0) {  // read-only segment: cached wide loads
      const _Float16* xp = p0b + kk;
#pragma unroll
      for (int i = 0; i < 8; ++i) {
        h8 v = *(const h8*)(xp + i * 8);
        dst[2 * i]     = (h4){v[0], v[1], v[2], v[3]};
        dst[2 * i + 1] = (h4){v[4], v[5], v[6], v[7]};
      }
    } else {                  // mutable state: LLC-coherent loads
      const _Float16* xp = (kk < L01) ? p1b + (kk - L0)
                         : (kk < L02) ? p2b + (kk - L01) : p3b + (kk - L02);
#pragma unroll
      for (int i = 0; i < 16; ++i) dst[i] = ld_cc8(xp + i * 4);
    }
  };
  ldch(0, xA);
  ldch(1, xB);
#pragma unroll 2
  for (int ch = 0; ch < NCH; ++ch) {
    h4 xC[16];
    int nx = ch + 2 < NCH ? ch + 2 : NCH - 1;
    ldch(nx, xC);
    const _Float16* wr = Wrow + ch * 64;
#pragma unroll
    for (int j = 0; j < 8; ++j) {
      h8 w = *(const h8*)(wr + j * 8);
      acc = d2((h2){w[0], w[1]}, (h2){xA[2 * j][0], xA[2 * j][1]}, acc);
      acc = d2((h2){w[2], w[3]}, (h2){xA[2 * j][2], xA[2 * j][3]}, acc);
      acc = d2((h2){w[4], w[5]}, (h2){xA[2 * j + 1][0], xA[2 * j + 1][1]}, acc);
      acc = d2((h2){w[6], w[7]}, (h2){xA[2 * j + 1][2], xA[2 * j + 1][3]}, acc);
    }
#pragma unroll
    for (int i = 0; i < 16; ++i) { xA[i] = xB[i]; xB[i] = xC[i]; }
  }
  zfull[b * 17 + c] = acc;
  __syncthreads();
  if (tid < 128) {
    int jj = tid >> 5, bb = tid & 31;
    float zi = zfull[bb * 17 + 4 * jj + 0] + gbl[4 * jj + 0];
    float zf = zfull[bb * 17 + 4 * jj + 1] + gbl[4 * jj + 1];
    float zg = zfull[bb * 17 + 4 * jj + 2] + gbl[4 * jj + 2];
    float zo = zfull[bb * 17 + 4 * jj + 3] + gbl[4 * jj + 3];
    float ig = fast_sigmoid(zi), fg = fast_sigmoid(zf);
    float gg = fast_tanh(zg), og = fast_sigmoid(zo);
    float cn = fg * cstL[jj * 32 + bb] + ig * gg;
    cstL[jj * 32 + bb] = cn;
    hbuf[bb * 4 + jj] = (_Float16)(og * fast_tanh(cn));
  }
  __syncthreads();
  if (tid < 32)  // pack 4 cols per b -> one 8B LLC-coherent store
    st_cc8(hout + tid * 1024 + B * 4, *(const h4*)(hbuf + tid * 4));
}

__device__ __forceinline__ void attn_phase(
    AttnS* A, const _Float16* __restrict__ memT, const _Float16* __restrict__ keys16,
    const _Float16* __restrict__ h1,
    const _Float16* __restrict__ qwT, const float* __restrict__ qb,
    const float* __restrict__ vw, const float* __restrict__ vb,
    const float* __restrict__ Mf, const float* __restrict__ Lbf,
    const _Float16* __restrict__ pwpT, const float* __restrict__ pb,
    const float* __restrict__ gb_out,
    float* __restrict__ wcumL, _Float16* __restrict__ ctxo,
    float* __restrict__ out, int b, int step, int tid) {
  // stage h1[b] (mutable) into LDS via cc loads; wl from LDS-resident wcum
  if (tid < 256) ((h4*)A->h1l)[tid] = ld_cc8(h1 + b * 1024 + tid * 4);
  if (tid < TIN + KSZ - 1) {
    int tt = tid - 15;
    A->wl[tid] = (tt >= 0 && tt < TIN) ? wcumL[tt] : 0.f;
  }
  __syncthreads();
  {  // qp partials: thread (a, kq); qwT read-only cached (L2-warm now)
    int a = tid & 127, kq = tid >> 7;
    const _Float16* hr = A->h1l + kq * 256;
    const _Float16* qr = qwT + a * 1024 + kq * 256;
    float s = 0.f;
#pragma unroll 8
    for (int i = 0; i < 32; ++i)
      s = dot8(*(const h8*)(hr + i * 8), *(const h8*)(qr + i * 8), s);
    A->qpart[kq * AA + a] = s;
  }
  __syncthreads();
  if (tid < AA)
    A->qp[tid] = A->qpart[tid] + A->qpart[AA + tid] + A->qpart[2 * AA + tid] +
                 A->qpart[3 * AA + tid] + qb[tid];
  __syncthreads();
  {  // energies: thread (t, ah)
    int t = tid & 255, ah = tid >> 8;
    const _Float16* keyrow = keys16 + ((size_t)(b * TIN + t)) * AA + ah * 64;
    h8 kv[8];
#pragma unroll
    for (int i = 0; i < 8; ++i) kv[i] = *(const h8*)(keyrow + i * 8);
    float e = (ah == 0) ? vb[0] : 0.f;
#pragma unroll
    for (int half = 0; half < 2; ++half) {
      int c2 = ah * 64 + half * 32;
      float l32[32];
      const float4* Lb4 = (const float4*)(Lbf + c2);
#pragma unroll
      for (int q = 0; q < 8; ++q) {
        float4 v = Lb4[q];
        l32[4 * q] = v.x; l32[4 * q + 1] = v.y; l32[4 * q + 2] = v.z; l32[4 * q + 3] = v.w;
      }
      for (int kk = 0; kk < KSZ; ++kk) {
        float wk = A->wl[t + kk];
        const float4* Mr = (const float4*)(Mf + kk * AA + c2);
#pragma unroll
        for (int q = 0; q < 8; ++q) {
          float4 m = Mr[q];
          l32[4 * q]     = fmaf(wk, m.x, l32[4 * q]);
          l32[4 * q + 1] = fmaf(wk, m.y, l32[4 * q + 1]);
          l32[4 * q + 2] = fmaf(wk, m.z, l32[4 * q + 2]);
          l32[4 * q + 3] = fmaf(wk, m.w, l32[4 * q + 3]);
        }
      }
#pragma unroll
      for (int aa = 0; aa < 32; ++aa) {
        float kf = (float)kv[(half * 32 + aa) >> 3][(half * 32 + aa) & 7];
        float u = fast_tanh(A->qp[c2 + aa] + kf + l32[aa]);
        e = fmaf(u, vw[c2 + aa], e);
      }
    }
    A->epart[ah * TIN + t] = e;
  }
  __syncthreads();
  float e = 0.f;
  if (tid < TIN) { e = A->epart[tid] + A->epart[TIN + tid]; A->red[tid] = e; }
  __syncthreads();
  for (int s = 128; s > 0; s >>= 1) {
    if (tid < s) A->red[tid] = fmaxf(A->red[tid], A->red[tid + s]);
    __syncthreads();
  }
  float mx = A->red[0];
  __syncthreads();
  float pp = 0.f;
  if (tid < TIN) { pp = __expf(e - mx); A->red[tid] = pp; }
  __syncthreads();
  for (int s = 128; s > 0; s >>= 1) {
    if (tid < s) A->red[tid] += A->red[tid + s];
    __syncthreads();
  }
  if (tid < TIN) {
    float w = pp / A->red[0];
    A->wsm16[tid] = (_Float16)w;
    wcumL[tid] += w;
    out[1036800 + (size_t)b * TOUT * TIN + step * TIN + tid] = w;
  }
  __syncthreads();
  {  // ctx = w @ memory via memT rows (read-only cached, L2-warm)
    const _Float16* mr = memT + ((size_t)(b * EE + tid)) * TIN;
    float s = 0.f;
#pragma unroll 8
    for (int i = 0; i < 32; ++i)
      s = dot8(*(const h8*)(A->wsm16 + i * 8), *(const h8*)(mr + i * 8), s);
    A->ctx16[tid] = (_Float16)s;
  }
  __syncthreads();
  if (tid < 128)  // publish ctx via cc stores
    st_cc8(ctxo + b * 512 + tid * 4, *(const h4*)(A->ctx16 + tid * 4));
  {  // mel(80)+gate(1): xo=[h1l,ctx16] all LDS; pwpT cached
    int kq = tid >> 7, oo = tid & 127;
    if (oo < 81) {
      const _Float16* pr = pwpT + oo * 1536 + kq * 384;
      float s = 0.f;
#pragma unroll 4
      for (int kk = 0; kk < 384; kk += 8) {
        int k = kq * 384 + kk;
        h8 xv = (k < DD) ? *(const h8*)(A->h1l + k) : *(const h8*)(A->ctx16 + (k - DD));
        s = dot8(xv, *(const h8*)(pr + kk), s);
      }
      A->pred[tid] = s;
    }
  }
  __syncthreads();
  if (tid < 81) {
    float s = A->pred[tid] + A->pred[128 + tid] + A->pred[256 + tid] + A->pred[384 + tid];
    if (tid < 80)
      out[(size_t)b * TOUT * NMEL + step * NMEL + tid] = s + pb[tid];
    else
      out[1024000 + b * TOUT + step] = s + gb_out[0];
  }
}

__global__ __launch_bounds__(512, 2) void k_decoder(
    const _Float16* __restrict__ memT, const _Float16* __restrict__ px,
    const _Float16* __restrict__ keys16, const _Float16* __restrict__ Wstage,
    const float* __restrict__ l0b, const float* __restrict__ l1b,
    const _Float16* __restrict__ qwT, const float* __restrict__ qb,
    const float* __restrict__ vw, const float* __restrict__ vb,
    const float* __restrict__ Mf, const float* __restrict__ Lbf,
    const _Float16* __restrict__ pwpT, const float* __restrict__ pb,
    const float* __restrict__ gb_out,
    char* state, float* out) {
  extern __shared__ char smem[];
  _Float16* Wl   = (_Float16*)smem;                // 139,520
  char* uni      = smem + 139520;                  // 12,416 union
  float* zfull   = (float*)uni;                    // 2,176 (lstm)
  _Float16* hbuf = (_Float16*)(uni + 2176);        // 256   (lstm)
  AttnS* A       = (AttnS*)uni;                    // 12,408 (attn)
  float* cst     = (float*)(smem + 151936);        // 1,024
  float* gb      = (float*)(smem + 152960);        // 128
  float* wcumL   = (float*)(smem + 153088);        // 1,024

  _Float16* h0b[2] = {(_Float16*)state, (_Float16*)(state + 65536)};
  _Float16* h1b[2] = {(_Float16*)(state + 131072), (_Float16*)(state + 196608)};
  _Float16* ctxb[2] = {(_Float16*)(state + 262144), (_Float16*)(state + 294912)};
  int* bar = (int*)(state + 360448);

  const int B = blockIdx.x, tid = threadIdx.x;

  {  // load this block's weight slice into LDS (read-only, once)
    const float4* src = (const float4*)(Wstage + (size_t)B * 16 * KP);
    float4* dst = (float4*)Wl;
    for (int i = tid; i < 16 * KP * 2 / 16; i += 512) dst[i] = src[i];
  }
  if (tid < 256) { cst[tid] = 0.f; wcumL[tid] = 0.f; }
  if (tid < 32) {
    int c = tid & 15;
    const float* bb = (tid < 16) ? l0b : l1b;
    gb[tid] = bb[(c & 3) * 1024 + B * 4 + (c >> 2)];
  }
  __syncthreads();

  for (int t = 0; t < TOUT; ++t) {
    const int p = t & 1, q = p ^ 1;
    // LSTM0: x = [px_t(ro,256) | ctx(cc,512) | h0_old(cc,1024)]
    lstm_phase<1792, 0, 256, 768, 1792>(Wl, zfull, hbuf, cst, gb,
                                        px + (size_t)t * 8192, ctxb[q], h0b[q],
                                        h0b[q], h0b[p], B, tid);
    gbar(bar, 3 * t + 0, tid);
    // LSTM1: x = [h0_new(cc,1024) | ctx(cc,512) | h1_old(cc,1024)]
    lstm_phase<2560, 1792, 0, 1024, 1536>(Wl, zfull, hbuf, cst + 128, gb + 16,
                                          px, h0b[p], ctxb[q],
                                          h1b[q], h1b[p], B, tid);
    gbar(bar, 3 * t + 1, tid);
    if (B < BB)
      attn_phase(A, memT, keys16, h1b[p], qwT, qb, vw, vb, Mf, Lbf,
                 pwpT, pb, gb_out, wcumL, ctxb[p], out, B, t, tid);
    gbar(bar, 3 * t + 2, tid);
  }
}

// ---------------- host ----------------
extern "C" void kernel_launch(void* const* d_in, const int* in_sizes, int n_in,
                              void* d_out, int out_size, void* d_ws, size_t ws_size,
                              hipStream_t stream) {
  const float* memory  = (const float*)d_in[0];
  const float* targets = (const float*)d_in[1];
  const float* p1w = (const float*)d_in[3];
  const float* p1b = (const float*)d_in[4];
  const float* p2w = (const float*)d_in[5];
  const float* p2b = (const float*)d_in[6];
  const float* l0k = (const float*)d_in[7];
  const float* l0r = (const float*)d_in[8];
  const float* l0b = (const float*)d_in[9];
  const float* l1k = (const float*)d_in[10];
  const float* l1r = (const float*)d_in[11];
  const float* l1b = (const float*)d_in[12];
  const float* qw  = (const float*)d_in[13];
  const float* qb  = (const float*)d_in[14];
  const float* mw  = (const float*)d_in[15];
  const float* mb  = (const float*)d_in[16];
  const float* vw  = (const float*)d_in[17];
  const float* vb  = (const float*)d_in[18];
  const float* cw  = (const float*)d_in[19];
  const float* cb  = (const float*)d_in[20];
  const float* ldw = (const float*)d_in[21];
  const float* ldb = (const float*)d_in[22];
  const float* pw  = (const float*)d_in[23];
  const float* pb  = (const float*)d_in[24];
  const float* gw  = (const float*)d_in[25];
  const float* gb  = (const float*)d_in[26];

  char* W = (char*)d_ws;
  _Float16* px16   = (_Float16*)(W + 0);           //  6,553,600
  _Float16* keys16 = (_Float16*)(W + 6553600);     //  2,097,152
  _Float16* memT16 = (_Float16*)(W + 8650752);     //  8,388,608
  _Float16* qwT16  = (_Float16*)(W + 17039360);    //    262,144
  _Float16* pwpT   = (_Float16*)(W + 17301504);    //    393,216
  float*    Mf     = (float*)   (W + 17694720);    //     15,872
  float*    Lbf    = (float*)   (W + 17710592);    //        512
  _Float16* Wstage = (_Float16*)(W + 17711104);    // 35,717,120
  char*     state  =             W + 53428224;     //    361,472
  float* out = (float*)d_out;

  // zero recurrent state + barrier counters (ws re-poisoned before every call)
  hipMemsetAsync(state, 0, 361472, stream);

  k_prenet<<<TOUT * BB, PRE, 0, stream>>>(targets, p1w, p1b, p2w, p2b, px16);
  k_keys<<<BB * TIN, AA, 0, stream>>>(memory, mw, mb, keys16);
  k_locM<<<1, AA, 0, stream>>>(cw, cb, ldw, ldb, Mf, Lbf);
  k_memT<<<4096, 256, 0, stream>>>(memory, memT16);
  k_castT<<<(131072 + 255) / 256, 256, 0, stream>>>(qw, qwT16);
  k_permP<<<768, 256, 0, stream>>>(pw, gw, pwpT);
  // weight slices: rows [l0k 0..767 | l0r 768..1791 | l1k 1792..3327 | l1r 3328..4351]
  k_perm<<<(768 * 1024 + 255) / 256, 256, 0, stream>>>(l0k, Wstage, 768, 0);
  k_perm<<<(1024 * 1024 + 255) / 256, 256, 0, stream>>>(l0r, Wstage, 1024, 768);
  k_perm<<<(1536 * 1024 + 255) / 256, 256, 0, stream>>>(l1k, Wstage, 1536, 1792);
  k_perm<<<(1024 * 1024 + 255) / 256, 256, 0, stream>>>(l1r, Wstage, 1024, 1792 + 1536);

  void* args[] = {(void*)&memT16, (void*)&px16, (void*)&keys16, (void*)&Wstage,
                  (void*)&l0b, (void*)&l1b, (void*)&qwT16, (void*)&qb,
                  (void*)&vw, (void*)&vb, (void*)&Mf, (void*)&Lbf,
                  (void*)&pwpT, (void*)&pb, (void*)&gb,
                  (void*)&state, (void*)&out};
  hipLaunchCooperativeKernel((const void*)k_decoder, dim3(256), dim3(512), args,
                             154112, stream);
}

// Round 10
// 50373.886 us; speedup vs baseline: 1.3211x; 1.1763x over previous
//
#include <hip/hip_runtime.h>
#include <math.h>

#define BB 32
#define TIN 256
#define TOUT 400
#define EE 512
#define AA 128
#define KSZ 31
#define PRE 256
#define DD 1024
#define NMEL 80
#define NF 32
#define KP 4360          // padded K-rows per LDS weight column (16B-aligned rows)

typedef _Float16 h2 __attribute__((ext_vector_type(2)));
typedef _Float16 h4 __attribute__((ext_vector_type(4)));
typedef _Float16 h8 __attribute__((ext_vector_type(8)));

__device__ __forceinline__ float fast_sigmoid(float x) { return 1.f / (1.f + __expf(-x)); }
__device__ __forceinline__ float fast_tanh(float x) {
  float ax = fabsf(x);
  float e = __expf(fminf(2.f * ax, 40.f));
  return copysignf((e - 1.f) / (e + 1.f), x);
}
__device__ __forceinline__ float d2(h2 a, h2 b, float c) {
#if __has_builtin(__builtin_amdgcn_fdot2)
  return __builtin_amdgcn_fdot2(a, b, c, false);
#else
  return fmaf((float)a[0], (float)b[0], fmaf((float)a[1], (float)b[1], c));
#endif
}
__device__ __forceinline__ float dot8(h8 a, h8 b, float c) {
  c = d2((h2){a[0], a[1]}, (h2){b[0], b[1]}, c);
  c = d2((h2){a[2], a[3]}, (h2){b[2], b[3]}, c);
  c = d2((h2){a[4], a[5]}, (h2){b[4], b[5]}, c);
  c = d2((h2){a[6], a[7]}, (h2){b[6], b[7]}, c);
  return c;
}

// ---- LLC-coherent 8B load/store (bypass L1/L2; no cache-maintenance fences) ----
__device__ __forceinline__ h4 ld_cc8(const _Float16* p) {
  unsigned long long v = __hip_atomic_load((const unsigned long long*)p,
                                           __ATOMIC_RELAXED, __HIP_MEMORY_SCOPE_SYSTEM);
  union { unsigned long long u; h4 h; } c; c.u = v; return c.h;
}
__device__ __forceinline__ void st_cc8(_Float16* p, h4 x) {
  union { unsigned long long u; h4 h; } c; c.h = x;
  __hip_atomic_store((unsigned long long*)p, c.u, __ATOMIC_RELAXED,
                     __HIP_MEMORY_SCOPE_SYSTEM);
}

// ---------------- setup kernels ----------------
__global__ void k_prenet(const float* __restrict__ targets,
                         const float* __restrict__ w1, const float* __restrict__ b1,
                         const float* __restrict__ w2, const float* __restrict__ b2,
                         _Float16* __restrict__ px) {
  int t = blockIdx.x >> 5, b = blockIdx.x & 31, j = threadIdx.x;
  __shared__ float din[NMEL];
  __shared__ float hl[PRE];
  if (j < NMEL) din[j] = (t == 0) ? 0.f : targets[(b * TOUT + (t - 1)) * NMEL + j];
  __syncthreads();
  float s = b1[j];
#pragma unroll
  for (int k = 0; k < NMEL; ++k) s = fmaf(din[k], w1[k * PRE + j], s);
  hl[j] = fmaxf(s, 0.f);
  __syncthreads();
  float s2 = b2[j];
  for (int k = 0; k < PRE; ++k) s2 = fmaf(hl[k], w2[k * PRE + j], s2);
  px[(size_t)t * 8192 + b * 256 + j] = (_Float16)fmaxf(s2, 0.f);
}

__global__ void k_keys(const float* __restrict__ memory, const float* __restrict__ mw,
                       const float* __restrict__ mb, _Float16* __restrict__ keys) {
  int row = blockIdx.x, a = threadIdx.x;
  __shared__ float mrow[EE];
  for (int i = a; i < EE; i += AA) mrow[i] = memory[row * EE + i];
  __syncthreads();
  float s = mb[a];
  for (int k = 0; k < EE; ++k) s = fmaf(mrow[k], mw[k * AA + a], s);
  keys[row * AA + a] = (_Float16)s;
}

__global__ void k_locM(const float* __restrict__ cw, const float* __restrict__ cb,
                       const float* __restrict__ ldw, const float* __restrict__ ldb,
                       float* __restrict__ M, float* __restrict__ Lb) {
  int a = threadIdx.x;
  for (int kk = 0; kk < KSZ; ++kk) {
    float s = 0.f;
    for (int f = 0; f < NF; ++f) s = fmaf(cw[kk * NF + f], ldw[f * AA + a], s);
    M[kk * AA + a] = s;
  }
  float s = ldb[a];
  for (int f = 0; f < NF; ++f) s = fmaf(cb[f], ldw[f * AA + a], s);
  Lb[a] = s;
}

// qw [1024][128] -> qwT [128][1024] fp16
__global__ void k_castT(const float* __restrict__ qw, _Float16* __restrict__ qwT) {
  int i = blockIdx.x * 256 + threadIdx.x;  // 131072
  int k = i >> 7, a = i & 127;
  qwT[a * 1024 + k] = (_Float16)qw[k * 128 + a];
}

// memory [b][t][e] -> memT [b][e][t] fp16, tiled transpose
__global__ void k_memT(const float* __restrict__ mem, _Float16* __restrict__ memT) {
  __shared__ _Float16 tile[32][33];
  int b = blockIdx.x >> 7;
  int tt = (blockIdx.x >> 4) & 7;
  int ee = blockIdx.x & 15;
  int r = threadIdx.x >> 5, cc = threadIdx.x & 31;
#pragma unroll
  for (int i = 0; i < 4; ++i) {
    int t = tt * 32 + r + i * 8, e = ee * 32 + cc;
    tile[r + i * 8][cc] = (_Float16)mem[((size_t)b * 256 + t) * 512 + e];
  }
  __syncthreads();
#pragma unroll
  for (int i = 0; i < 4; ++i) {
    int e = ee * 32 + r + i * 8, t = tt * 32 + cc;
    memT[((size_t)b * 512 + e) * 256 + t] = tile[cc][r + i * 8];
  }
}

// proj+gate weights transposed: pwpT[o][k], o<80 = mel col o, o=80 = gate
__global__ void k_permP(const float* __restrict__ pw, const float* __restrict__ gw,
                        _Float16* __restrict__ pwpT) {
  int i = blockIdx.x * 256 + threadIdx.x;  // 128*1536
  int o = i / 1536, k = i % 1536;
  float v = (o < 80) ? pw[k * 80 + o] : ((o == 80) ? gw[k] : 0.f);
  pwpT[i] = (_Float16)v;
}

// gate-interleave + per-block-slice permute: col p=4j+g; block B=j>>2 owns 16
// cols; c=4*(j&3)+g; dst[(B*16+c)*KP + row_off + k]
__global__ void k_perm(const float* __restrict__ src, _Float16* __restrict__ dst,
                       int rows, int row_off) {
  int idx = blockIdx.x * 256 + threadIdx.x;
  int k = idx >> 10, j = idx & 1023;
  if (k >= rows) return;
  const float* s = src + (size_t)k * 4096 + j;
  int base = (j >> 2) * 16 + 4 * (j & 3);
#pragma unroll
  for (int g = 0; g < 4; ++g)
    dst[(size_t)(base + g) * KP + row_off + k] = (_Float16)s[g * 1024];
}

// ---------------- persistent decoder ----------------
struct __align__(16) AttnS {
  _Float16 h1l[1024];
  _Float16 ctx16[EE];
  _Float16 wsm16[TIN];
  float wl[TIN + KSZ - 1];
  float qpart[512];
  float qp[AA];
  float red[TIN];
  float epart[512];
  float pred[512];
};

// fence-free grid barrier; BUSY poll (no s_sleep) — keep CUs active so DVFS
// doesn't downclock the chip during the wait (round 6-9 plateau hypothesis).
__device__ __forceinline__ void gbar(int* bar, int ord, int tid) {
  __syncthreads();
  if (tid == 0) {
    __builtin_amdgcn_fence(__ATOMIC_RELEASE, "workgroup");
    int g = blockIdx.x & 7;
    int old = __hip_atomic_fetch_add(bar + g * 16, 1, __ATOMIC_RELAXED,
                                     __HIP_MEMORY_SCOPE_SYSTEM);
    if ((old & 31) == 31) {
      int e = __hip_atomic_fetch_add(bar + 128, 1, __ATOMIC_RELAXED,
                                     __HIP_MEMORY_SCOPE_SYSTEM);
      if (e == 8 * ord + 7) {
#pragma unroll
        for (int d = 0; d < 8; ++d)
          __hip_atomic_store(bar + 144 + d * 16, ord + 1, __ATOMIC_RELAXED,
                             __HIP_MEMORY_SCOPE_SYSTEM);
      }
    }
    while (__hip_atomic_load(bar + 144 + g * 16, __ATOMIC_RELAXED,
                             __HIP_MEMORY_SCOPE_SYSTEM) < ord + 1) { /* busy */ }
    __builtin_amdgcn_fence(__ATOMIC_ACQUIRE, "workgroup");
  }
  __syncthreads();
}

// LSTM phase: thread (c in 16, b in 32), full K, compact per-segment loops
// (rounds 6-9 fully unrolled ~36KB bodies -> I-cache streaming each phase).
// ro segment = cached loads (read-only px); cc segments = LLC-coherent state.
template <int LRO, int LA, int LB, int LC, int WOFF>
__device__ __forceinline__ void lstm_phase(
    const _Float16* __restrict__ Wl, float* __restrict__ zfull,
    _Float16* __restrict__ hbuf, float* __restrict__ cstL,
    const float* __restrict__ gbl,
    const _Float16* __restrict__ ro, const _Float16* __restrict__ ca,
    const _Float16* __restrict__ cb2, const _Float16* __restrict__ cc3,
    _Float16* __restrict__ hout, int B, int tid) {
  const int c = tid & 15, b = tid >> 4;
  const _Float16* Wrow = Wl + c * KP + WOFF;
  float acc = 0.f;
  if (LRO > 0) {
    const _Float16* xp = ro + b * LRO;
#pragma unroll 4
    for (int k = 0; k < LRO; k += 8)
      acc = dot8(*(const h8*)(Wrow + k), *(const h8*)(xp + k), acc);
    Wrow += LRO;
  }
  {
    const _Float16* xp = ca + b * LA;
#pragma unroll 4
    for (int k = 0; k < LA; k += 8) {
      h4 x0 = ld_cc8(xp + k);
      h4 x1 = ld_cc8(xp + k + 4);
      h8 w = *(const h8*)(Wrow + k);
      acc = d2((h2){w[0], w[1]}, (h2){x0[0], x0[1]}, acc);
      acc = d2((h2){w[2], w[3]}, (h2){x0[2], x0[3]}, acc);
      acc = d2((h2){w[4], w[5]}, (h2){x1[0], x1[1]}, acc);
      acc = d2((h2){w[6], w[7]}, (h2){x1[2], x1[3]}, acc);
    }
    Wrow += LA;
  }
  if (LB > 0) {
    const _Float16* xp = cb2 + b * LB;
#pragma unroll 4
    for (int k = 0; k < LB; k += 8) {
      h4 x0 = ld_cc8(xp + k);
      h4 x1 = ld_cc8(xp + k + 4);
      h8 w = *(const h8*)(Wrow + k);
      acc = d2((h2){w[0], w[1]}, (h2){x0[0], x0[1]}, acc);
      acc = d2((h2){w[2], w[3]}, (h2){x0[2], x0[3]}, acc);
      acc = d2((h2){w[4], w[5]}, (h2){x1[0], x1[1]}, acc);
      acc = d2((h2){w[6], w[7]}, (h2){x1[2], x1[3]}, acc);
    }
    Wrow += LB;
  }
  if (LC > 0) {
    const _Float16* xp = cc3 + b * LC;
#pragma unroll 4
    for (int k = 0; k < LC; k += 8) {
      h4 x0 = ld_cc8(xp + k);
      h4 x1 = ld_cc8(xp + k + 4);
      h8 w = *(const h8*)(Wrow + k);
      acc = d2((h2){w[0], w[1]}, (h2){x0[0], x0[1]}, acc);
      acc = d2((h2){w[2], w[3]}, (h2){x0[2], x0[3]}, acc);
      acc = d2((h2){w[4], w[5]}, (h2){x1[0], x1[1]}, acc);
      acc = d2((h2){w[6], w[7]}, (h2){x1[2], x1[3]}, acc);
    }
  }
  zfull[b * 17 + c] = acc;
  __syncthreads();
  if (tid < 128) {
    int jj = tid >> 5, bb = tid & 31;
    float zi = zfull[bb * 17 + 4 * jj + 0] + gbl[4 * jj + 0];
    float zf = zfull[bb * 17 + 4 * jj + 1] + gbl[4 * jj + 1];
    float zg = zfull[bb * 17 + 4 * jj + 2] + gbl[4 * jj + 2];
    float zo = zfull[bb * 17 + 4 * jj + 3] + gbl[4 * jj + 3];
    float ig = fast_sigmoid(zi), fg = fast_sigmoid(zf);
    float gg = fast_tanh(zg), og = fast_sigmoid(zo);
    float cn = fg * cstL[jj * 32 + bb] + ig * gg;
    cstL[jj * 32 + bb] = cn;
    hbuf[bb * 4 + jj] = (_Float16)(og * fast_tanh(cn));
  }
  __syncthreads();
  if (tid < 32)
    st_cc8(hout + tid * 1024 + B * 4, *(const h4*)(hbuf + tid * 4));
}

__device__ __forceinline__ void attn_phase(
    AttnS* A, const _Float16* __restrict__ memT, const _Float16* __restrict__ keys16,
    const _Float16* __restrict__ h1,
    const _Float16* __restrict__ qwT, const float* __restrict__ qb,
    const float* __restrict__ vw, const float* __restrict__ vb,
    const float* __restrict__ Mf, const float* __restrict__ Lbf,
    const _Float16* __restrict__ pwpT, const float* __restrict__ pb,
    const float* __restrict__ gb_out,
    float* __restrict__ wcumL, _Float16* __restrict__ ctxo,
    float* __restrict__ out, int b, int step, int tid) {
  if (tid < 256) ((h4*)A->h1l)[tid] = ld_cc8(h1 + b * 1024 + tid * 4);
  if (tid < TIN + KSZ - 1) {
    int tt = tid - 15;
    A->wl[tid] = (tt >= 0 && tt < TIN) ? wcumL[tt] : 0.f;
  }
  __syncthreads();
  {  // qp partials
    int a = tid & 127, kq = tid >> 7;
    const _Float16* hr = A->h1l + kq * 256;
    const _Float16* qr = qwT + a * 1024 + kq * 256;
    float s = 0.f;
#pragma unroll 4
    for (int i = 0; i < 32; ++i)
      s = dot8(*(const h8*)(hr + i * 8), *(const h8*)(qr + i * 8), s);
    A->qpart[kq * AA + a] = s;
  }
  __syncthreads();
  if (tid < AA)
    A->qp[tid] = A->qpart[tid] + A->qpart[AA + tid] + A->qpart[2 * AA + tid] +
                 A->qpart[3 * AA + tid] + qb[tid];
  __syncthreads();
  {  // energies
    int t = tid & 255, ah = tid >> 8;
    const _Float16* keyrow = keys16 + ((size_t)(b * TIN + t)) * AA + ah * 64;
    h8 kv[8];
#pragma unroll
    for (int i = 0; i < 8; ++i) kv[i] = *(const h8*)(keyrow + i * 8);
    float e = (ah == 0) ? vb[0] : 0.f;
#pragma unroll
    for (int half = 0; half < 2; ++half) {
      int c2 = ah * 64 + half * 32;
      float l32[32];
      const float4* Lb4 = (const float4*)(Lbf + c2);
#pragma unroll
      for (int q = 0; q < 8; ++q) {
        float4 v = Lb4[q];
        l32[4 * q] = v.x; l32[4 * q + 1] = v.y; l32[4 * q + 2] = v.z; l32[4 * q + 3] = v.w;
      }
      for (int kk = 0; kk < KSZ; ++kk) {
        float wk = A->wl[t + kk];
        const float4* Mr = (const float4*)(Mf + kk * AA + c2);
#pragma unroll
        for (int q = 0; q < 8; ++q) {
          float4 m = Mr[q];
          l32[4 * q]     = fmaf(wk, m.x, l32[4 * q]);
          l32[4 * q + 1] = fmaf(wk, m.y, l32[4 * q + 1]);
          l32[4 * q + 2] = fmaf(wk, m.z, l32[4 * q + 2]);
          l32[4 * q + 3] = fmaf(wk, m.w, l32[4 * q + 3]);
        }
      }
#pragma unroll
      for (int aa = 0; aa < 32; ++aa) {
        float kf = (float)kv[(half * 32 + aa) >> 3][(half * 32 + aa) & 7];
        float u = fast_tanh(A->qp[c2 + aa] + kf + l32[aa]);
        e = fmaf(u, vw[c2 + aa], e);
      }
    }
    A->epart[ah * TIN + t] = e;
  }
  __syncthreads();
  float e = 0.f;
  if (tid < TIN) { e = A->epart[tid] + A->epart[TIN + tid]; A->red[tid] = e; }
  __syncthreads();
  for (int s = 128; s > 0; s >>= 1) {
    if (tid < s) A->red[tid] = fmaxf(A->red[tid], A->red[tid + s]);
    __syncthreads();
  }
  float mx = A->red[0];
  __syncthreads();
  float pp = 0.f;
  if (tid < TIN) { pp = __expf(e - mx); A->red[tid] = pp; }
  __syncthreads();
  for (int s = 128; s > 0; s >>= 1) {
    if (tid < s) A->red[tid] += A->red[tid + s];
    __syncthreads();
  }
  if (tid < TIN) {
    float w = pp / A->red[0];
    A->wsm16[tid] = (_Float16)w;
    wcumL[tid] += w;
    out[1036800 + (size_t)b * TOUT * TIN + step * TIN + tid] = w;
  }
  __syncthreads();
  {  // ctx = w @ memory via memT rows (read-only, L2-warm)
    const _Float16* mr = memT + ((size_t)(b * EE + tid)) * TIN;
    float s = 0.f;
#pragma unroll 4
    for (int i = 0; i < 32; ++i)
      s = dot8(*(const h8*)(A->wsm16 + i * 8), *(const h8*)(mr + i * 8), s);
    A->ctx16[tid] = (_Float16)s;
  }
  __syncthreads();
  if (tid < 128)
    st_cc8(ctxo + b * 512 + tid * 4, *(const h4*)(A->ctx16 + tid * 4));
  {  // mel(80)+gate(1)
    int kq = tid >> 7, oo = tid & 127;
    if (oo < 81) {
      const _Float16* pr = pwpT + oo * 1536 + kq * 384;
      float s = 0.f;
#pragma unroll 2
      for (int kk = 0; kk < 384; kk += 8) {
        int k = kq * 384 + kk;
        h8 xv = (k < DD) ? *(const h8*)(A->h1l + k) : *(const h8*)(A->ctx16 + (k - DD));
        s = dot8(xv, *(const h8*)(pr + kk), s);
      }
      A->pred[tid] = s;
    }
  }
  __syncthreads();
  if (tid < 81) {
    float s = A->pred[tid] + A->pred[128 + tid] + A->pred[256 + tid] + A->pred[384 + tid];
    if (tid < 80)
      out[(size_t)b * TOUT * NMEL + step * NMEL + tid] = s + pb[tid];
    else
      out[1024000 + b * TOUT + step] = s + gb_out[0];
  }
}

__global__ __launch_bounds__(512, 2) void k_decoder(
    const _Float16* __restrict__ memT, const _Float16* __restrict__ px,
    const _Float16* __restrict__ keys16, const _Float16* __restrict__ Wstage,
    const float* __restrict__ l0b, const float* __restrict__ l1b,
    const _Float16* __restrict__ qwT, const float* __restrict__ qb,
    const float* __restrict__ vw, const float* __restrict__ vb,
    const float* __restrict__ Mf, const float* __restrict__ Lbf,
    const _Float16* __restrict__ pwpT, const float* __restrict__ pb,
    const float* __restrict__ gb_out,
    char* state, float* out) {
  extern __shared__ char smem[];
  _Float16* Wl   = (_Float16*)smem;                // 139,520
  char* uni      = smem + 139520;                  // 12,416 union
  float* zfull   = (float*)uni;                    // 2,176 (lstm)
  _Float16* hbuf = (_Float16*)(uni + 2176);        // 256   (lstm)
  AttnS* A       = (AttnS*)uni;                    // 12,408 (attn)
  float* cst     = (float*)(smem + 151936);        // 1,024
  float* gb      = (float*)(smem + 152960);        // 128
  float* wcumL   = (float*)(smem + 153088);        // 1,024

  _Float16* h0b[2] = {(_Float16*)state, (_Float16*)(state + 65536)};
  _Float16* h1b[2] = {(_Float16*)(state + 131072), (_Float16*)(state + 196608)};
  _Float16* ctxb[2] = {(_Float16*)(state + 262144), (_Float16*)(state + 294912)};
  int* bar = (int*)(state + 360448);

  const int B = blockIdx.x, tid = threadIdx.x;

  {  // load this block's weight slice into LDS (read-only, once)
    const float4* src = (const float4*)(Wstage + (size_t)B * 16 * KP);
    float4* dst = (float4*)Wl;
    for (int i = tid; i < 16 * KP * 2 / 16; i += 512) dst[i] = src[i];
  }
  if (tid < 256) { cst[tid] = 0.f; wcumL[tid] = 0.f; }
  if (tid < 32) {
    int c = tid & 15;
    const float* bb = (tid < 16) ? l0b : l1b;
    gb[tid] = bb[(c & 3) * 1024 + B * 4 + (c >> 2)];
  }
  __syncthreads();

  for (int t = 0; t < TOUT; ++t) {
    const int p = t & 1, q = p ^ 1;
    // LSTM0: x = [px_t(ro,256) | ctx(cc,512) | h0_old(cc,1024)]
    lstm_phase<256, 512, 1024, 0, 0>(Wl, zfull, hbuf, cst, gb,
                                     px + (size_t)t * 8192, ctxb[q], h0b[q],
                                     h0b[q], h0b[p], B, tid);
    gbar(bar, 3 * t + 0, tid);
    // LSTM1: x = [h0_new(cc,1024) | ctx(cc,512) | h1_old(cc,1024)]
    lstm_phase<0, 1024, 512, 1024, 1792>(Wl, zfull, hbuf, cst + 128, gb + 16,
                                         px, h0b[p], ctxb[q],
                                         h1b[q], h1b[p], B, tid);
    gbar(bar, 3 * t + 1, tid);
    if (B < BB)
      attn_phase(A, memT, keys16, h1b[p], qwT, qb, vw, vb, Mf, Lbf,
                 pwpT, pb, gb_out, wcumL, ctxb[p], out, B, t, tid);
    gbar(bar, 3 * t + 2, tid);
  }
}

// ---------------- host ----------------
extern "C" void kernel_launch(void* const* d_in, const int* in_sizes, int n_in,
                              void* d_out, int out_size, void* d_ws, size_t ws_size,
                              hipStream_t stream) {
  const float* memory  = (const float*)d_in[0];
  const float* targets = (const float*)d_in[1];
  const float* p1w = (const float*)d_in[3];
  const float* p1b = (const float*)d_in[4];
  const float* p2w = (const float*)d_in[5];
  const float* p2b = (const float*)d_in[6];
  const float* l0k = (const float*)d_in[7];
  const float* l0r = (const float*)d_in[8];
  const float* l0b = (const float*)d_in[9];
  const float* l1k = (const float*)d_in[10];
  const float* l1r = (const float*)d_in[11];
  const float* l1b = (const float*)d_in[12];
  const float* qw  = (const float*)d_in[13];
  const float* qb  = (const float*)d_in[14];
  const float* mw  = (const float*)d_in[15];
  const float* mb  = (const float*)d_in[16];
  const float* vw  = (const float*)d_in[17];
  const float* vb  = (const float*)d_in[18];
  const float* cw  = (const float*)d_in[19];
  const float* cb  = (const float*)d_in[20];
  const float* ldw = (const float*)d_in[21];
  const float* ldb = (const float*)d_in[22];
  const float* pw  = (const float*)d_in[23];
  const float* pb  = (const float*)d_in[24];
  const float* gw  = (const float*)d_in[25];
  const float* gb  = (const float*)d_in[26];

  char* W = (char*)d_ws;
  _Float16* px16   = (_Float16*)(W + 0);           //  6,553,600
  _Float16* keys16 = (_Float16*)(W + 6553600);     //  2,097,152
  _Float16* memT16 = (_Float16*)(W + 8650752);     //  8,388,608
  _Float16* qwT16  = (_Float16*)(W + 17039360);    //    262,144
  _Float16* pwpT   = (_Float16*)(W + 17301504);    //    393,216
  float*    Mf     = (float*)   (W + 17694720);    //     15,872
  float*    Lbf    = (float*)   (W + 17710592);    //        512
  _Float16* Wstage = (_Float16*)(W + 17711104);    // 35,717,120
  char*     state  =             W + 53428224;     //    361,472
  float* out = (float*)d_out;

  // zero recurrent state + barrier counters (ws re-poisoned before every call)
  hipMemsetAsync(state, 0, 361472, stream);

  k_prenet<<<TOUT * BB, PRE, 0, stream>>>(targets, p1w, p1b, p2w, p2b, px16);
  k_keys<<<BB * TIN, AA, 0, stream>>>(memory, mw, mb, keys16);
  k_locM<<<1, AA, 0, stream>>>(cw, cb, ldw, ldb, Mf, Lbf);
  k_memT<<<4096, 256, 0, stream>>>(memory, memT16);
  k_castT<<<(131072 + 255) / 256, 256, 0, stream>>>(qw, qwT16);
  k_permP<<<768, 256, 0, stream>>>(pw, gw, pwpT);
  // weight slices: rows [l0k 0..767 | l0r 768..1791 | l1k 1792..3327 | l1r 3328..4351]
  k_perm<<<(768 * 1024 + 255) / 256, 256, 0, stream>>>(l0k, Wstage, 768, 0);
  k_perm<<<(1024 * 1024 + 255) / 256, 256, 0, stream>>>(l0r, Wstage, 1024, 768);
  k_perm<<<(1536 * 1024 + 255) / 256, 256, 0, stream>>>(l1k, Wstage, 1536, 1792);
  k_perm<<<(1024 * 1024 + 255) / 256, 256, 0, stream>>>(l1r, Wstage, 1024, 1792 + 1536);

  void* args[] = {(void*)&memT16, (void*)&px16, (void*)&keys16, (void*)&Wstage,
                  (void*)&l0b, (void*)&l1b, (void*)&qwT16, (void*)&qb,
                  (void*)&vw, (void*)&vb, (void*)&Mf, (void*)&Lbf,
                  (void*)&pwpT, (void*)&pb, (void*)&gb,
                  (void*)&state, (void*)&out};
  hipLaunchCooperativeKernel((const void*)k_decoder, dim3(256), dim3(512), args,
                             154112, stream);
}